// Round 10
// baseline (950.550 us; speedup 1.0000x reference)
//
#include <hip/hip_runtime.h>

#define N_VUL 100000
#define N_OTH 20000
#define E_NUM 400000
#define K_DIM 256
#define D_OUT 128
#define EPS 1e-8f
#define LDW 264   // padded LDS row (bf16 elems)

#define NCV 391               // ceil(N_VUL/256) coarse buckets (vul side)
#define NCO_J 79              // ceil(N_OTH/256) per etype j (oth side)
#define NC (NCV + 4 * NCO_J)  // 707 total coarse buckets
#define TOT_E (8 * E_NUM)     // 3,200,000 edges
#define CHUNK 8192            // edges per cstage block
#define VCAP 5120             // max edges per vul bucket
#define OCAP 6144             // max edges per oth bucket
#define VKEYS (4 * N_VUL)
#define KEYS  (4 * N_VUL + 4 * N_OTH)
#define NVB (N_VUL / 4)       // 25000 vul gather blocks

typedef __attribute__((ext_vector_type(8))) short bf16x8;
typedef __attribute__((ext_vector_type(4))) float f32x4;

static const size_t NV128 = (size_t)N_VUL * 128;
static const size_t NO128 = (size_t)N_OTH * 128;

__device__ __forceinline__ unsigned short f2b(float f) {
    unsigned int u = __float_as_uint(f);
    u += 0x7FFFu + ((u >> 16) & 1u);
    return (unsigned short)(u >> 16);
}
__device__ __forceinline__ float b2f(unsigned short h) {
    return __uint_as_float(((unsigned int)h) << 16);
}

// ---------------- src/dst disambiguation probe (proven) ----------------
__global__ __launch_bounds__(256)
void probe_idx(const int* __restrict__ cand, int* __restrict__ flag)
{
    const int e = blockIdx.x * 256 + threadIdx.x;
    if (e >= E_NUM) return;
    int v = cand[e];
    if (v < 0 || v >= N_OTH) atomicOr(flag, 1);
}

// ---------------- weight pack (proven) ----------------
// order: 0=Wn0, 1..4=We4..7, 5=Wn1,6=We0, 7=Wn2,8=We1, 9=Wn3,10=We2, 11=Wn4,12=We3
__global__ __launch_bounds__(256)
void pack_w(const float* __restrict__ We, const float* __restrict__ Wn,
            unsigned short* __restrict__ Wb)
{
    const int id = blockIdx.x * 256 + threadIdx.x;
    if (id >= 13 * 32768) return;
    const int wp = id >> 15;
    const int n  = (id >> 8) & 127;
    const int k  = id & 255;
    const float* S;
    if (wp == 0)      S = Wn;
    else if (wp <= 4) S = We + (size_t)(3 + wp) * 32768;
    else if (wp & 1)  S = Wn + (size_t)((wp - 3) >> 1) * 32768;
    else              S = We + (size_t)((wp - 6) >> 1) * 32768;
    Wb[id] = f2b(S[k * D_OUT + n]);
}

// ---------------- fused MFMA projection + row-norm epilogue ----------------
// w==0 -> f32 ht (+bias) into outF (ld 256), recip norm -> rnHt
// w>0  -> bf16 table (w-1), recip norm (of rounded values) -> rnTab[(w-1)*N+row]
__global__ __launch_bounds__(256)
void proj_mfma(const float* __restrict__ X, const unsigned short* __restrict__ Wb,
               const float* __restrict__ bias, float* __restrict__ outF,
               unsigned short* __restrict__ tabs, int NW, int N,
               float* __restrict__ rnHt, float* __restrict__ rnTab)
{
    __shared__ unsigned short xs[64 * LDW];
    __shared__ float rs[64];
    const int tid  = threadIdx.x;
    const int wave = tid >> 6, lane = tid & 63;
    const int r0   = blockIdx.x * 64;

    #pragma unroll
    for (int c = 0; c < 16; ++c) {
        int f = c * 256 + tid;
        int row = f >> 6, col4 = f & 63;
        int gr = r0 + row; if (gr >= N) gr = N - 1;
        float4 v = *(const float4*)(X + (size_t)gr * K_DIM + col4 * 4);
        unsigned short* p = xs + row * LDW + col4 * 4;
        p[0] = f2b(v.x); p[1] = f2b(v.y); p[2] = f2b(v.z); p[3] = f2b(v.w);
    }
    __syncthreads();

    const int n0   = wave * 32;
    const int arow = lane & 15, akd = (lane >> 4) * 8;
    const int bcol = lane & 15, bkd = (lane >> 4) * 8;
    const int rsub = (lane >> 4) * 4;

    float bias0 = 0.f, bias1 = 0.f;
    if (bias) { bias0 = bias[n0 + bcol]; bias1 = bias[n0 + 16 + bcol]; }

    for (int w = 0; w < NW; ++w) {
        f32x4 acc[4][2];
        #pragma unroll
        for (int m = 0; m < 4; ++m) {
            acc[m][0] = (f32x4){0.f, 0.f, 0.f, 0.f};
            acc[m][1] = (f32x4){0.f, 0.f, 0.f, 0.f};
        }
        const unsigned short* wb = Wb + (size_t)w * 128 * 256;
        #pragma unroll
        for (int k = 0; k < 8; ++k) {
            bf16x8 b0 = *(const bf16x8*)(wb + (size_t)(n0 + bcol) * 256 + k * 32 + bkd);
            bf16x8 b1 = *(const bf16x8*)(wb + (size_t)(n0 + 16 + bcol) * 256 + k * 32 + bkd);
            #pragma unroll
            for (int m = 0; m < 4; ++m) {
                bf16x8 a = *(const bf16x8*)(xs + (m * 16 + arow) * LDW + k * 32 + akd);
                acc[m][0] = __builtin_amdgcn_mfma_f32_16x16x32_bf16(a, b0, acc[m][0], 0, 0, 0);
                acc[m][1] = __builtin_amdgcn_mfma_f32_16x16x32_bf16(a, b1, acc[m][1], 0, 0, 0);
            }
        }
        __syncthreads();                       // rs reuse: prior weight's reads done
        if (tid < 64) rs[tid] = 0.f;
        __syncthreads();

        if (w == 0) {
            #pragma unroll
            for (int m = 0; m < 4; ++m)
                #pragma unroll
                for (int j = 0; j < 4; ++j) {
                    const int row = r0 + m * 16 + rsub + j;
                    if (row < N) {
                        const float v0 = acc[m][0][j] + bias0;
                        const float v1 = acc[m][1][j] + bias1;
                        outF[(size_t)row * 256 + n0 + bcol]      = v0;
                        outF[(size_t)row * 256 + n0 + 16 + bcol] = v1;
                        atomicAdd(&rs[m * 16 + rsub + j], v0 * v0 + v1 * v1);
                    }
                }
        } else {
            unsigned short* tw = tabs + (size_t)(w - 1) * N * D_OUT;
            #pragma unroll
            for (int m = 0; m < 4; ++m)
                #pragma unroll
                for (int j = 0; j < 4; ++j) {
                    const int row = r0 + m * 16 + rsub + j;
                    if (row < N) {
                        const unsigned short h0 = f2b(acc[m][0][j]);
                        const unsigned short h1 = f2b(acc[m][1][j]);
                        tw[(size_t)row * D_OUT + n0 + bcol]      = h0;
                        tw[(size_t)row * D_OUT + n0 + 16 + bcol] = h1;
                        const float v0 = b2f(h0), v1 = b2f(h1);
                        atomicAdd(&rs[m * 16 + rsub + j], v0 * v0 + v1 * v1);
                    }
                }
        }
        __syncthreads();
        if (tid < 64) {
            const int row = r0 + tid;
            if (row < N) {
                const float rn = 1.f / fmaxf(sqrtf(rs[tid]), EPS);
                if (w == 0) rnHt[row] = rn;
                else        rnTab[(size_t)(w - 1) * N + row] = rn;
            }
        }
    }
}

// ---------------- edge -> (coarse bucket, packed entry) (proven) ----------------
__device__ __forceinline__ void edge_cd(const int* __restrict__ srcp,
                                        const int* __restrict__ dstp,
                                        int id, int* c_out, unsigned* entry_out)
{
    const int et = id / E_NUM;
    const int e  = id - et * E_NUM;
    int d = dstp[(size_t)et * E_NUM + e];
    if (et < 4) {
        d = d < 0 ? 0 : (d >= N_VUL ? N_VUL - 1 : d);
        *c_out = d >> 8;
        if (entry_out) {
            int s = srcp[(size_t)et * E_NUM + e];
            s = s < 0 ? 0 : (s >= N_OTH ? N_OTH - 1 : s);
            *entry_out = ((unsigned)(((d & 255) << 2) | et) << 17) | (unsigned)s;
        }
    } else {
        d = d < 0 ? 0 : (d >= N_OTH ? N_OTH - 1 : d);
        *c_out = NCV + (et - 4) * NCO_J + (d >> 8);
        if (entry_out) {
            int s = srcp[(size_t)et * E_NUM + e];
            s = s < 0 ? 0 : (s >= N_VUL ? N_VUL - 1 : s);
            *entry_out = ((unsigned)(d & 255) << 17) | (unsigned)s;
        }
    }
}

// ---------------- coarse histogram (proven) ----------------
__global__ __launch_bounds__(256)
void chist(const int* __restrict__ pA, const int* __restrict__ pB,
           const int* __restrict__ flag, int* __restrict__ ccnt)
{
    __shared__ int h[NC];
    for (int i = threadIdx.x; i < NC; i += 256) h[i] = 0;
    __syncthreads();
    const int flagv = *flag;
    const int* srcp = flagv ? pB : pA;
    const int* dstp = flagv ? pA : pB;
    const int base = blockIdx.x * 16384;
    for (int t = 0; t < 64; ++t) {
        const int id = base + t * 256 + threadIdx.x;
        if (id < TOT_E) {
            int c; edge_cd(srcp, dstp, id, &c, nullptr);
            atomicAdd(&h[c], 1);
        }
    }
    __syncthreads();
    for (int i = threadIdx.x; i < NC; i += 256)
        if (h[i]) atomicAdd(&ccnt[i], h[i]);
}

// ---------------- exclusive scan of coarse counts; writes offs[KEYS] ----------------
__global__ __launch_bounds__(256)
void cscan(const int* __restrict__ ccnt, int* __restrict__ cbase,
           int* __restrict__ ccur, int* __restrict__ offs)
{
    __shared__ int sh[256];
    __shared__ int carry;
    if (threadIdx.x == 0) carry = 0;
    __syncthreads();
    for (int b = 0; b < NC; b += 256) {
        const int i = b + threadIdx.x;
        const int v = (i < NC) ? ccnt[i] : 0;
        sh[threadIdx.x] = v;
        __syncthreads();
        for (int st = 1; st < 256; st <<= 1) {
            int t = (threadIdx.x >= st) ? sh[threadIdx.x - st] : 0;
            __syncthreads();
            sh[threadIdx.x] += t;
            __syncthreads();
        }
        const int excl = carry + sh[threadIdx.x] - v;
        if (i < NC) { cbase[i] = excl; ccur[i] = excl; }
        __syncthreads();
        if (threadIdx.x == 255) carry += sh[255];
        __syncthreads();
    }
    if (threadIdx.x == 0) offs[KEYS] = carry;   // == TOT_E
}

// ---------------- staged scatter (proven) ----------------
__global__ __launch_bounds__(256)
void cstage(const int* __restrict__ pA, const int* __restrict__ pB,
            const int* __restrict__ flag, int* __restrict__ ccur,
            unsigned* __restrict__ staging)
{
    __shared__ unsigned outE[CHUNK];
    __shared__ unsigned short binof[CHUNK];
    __shared__ int foff[NC];
    __shared__ int fcur[NC];
    __shared__ int gb[NC];
    __shared__ int sh[256];
    __shared__ int carry;

    const int flagv = *flag;
    const int* srcp = flagv ? pB : pA;
    const int* dstp = flagv ? pA : pB;
    const int base = blockIdx.x * CHUNK;
    const int n = (base + CHUNK <= TOT_E) ? CHUNK : (TOT_E - base);

    for (int i = threadIdx.x; i < NC; i += 256) foff[i] = 0;
    if (threadIdx.x == 0) carry = 0;
    __syncthreads();

    for (int t = 0; t < CHUNK / 256; ++t) {
        const int k = t * 256 + threadIdx.x;
        if (k < n) {
            int c; edge_cd(srcp, dstp, base + k, &c, nullptr);
            atomicAdd(&foff[c], 1);
        }
    }
    __syncthreads();

    for (int b = 0; b < NC; b += 256) {
        const int i = b + threadIdx.x;
        const int v = (i < NC) ? foff[i] : 0;
        sh[threadIdx.x] = v;
        __syncthreads();
        for (int st = 1; st < 256; st <<= 1) {
            int t = (threadIdx.x >= st) ? sh[threadIdx.x - st] : 0;
            __syncthreads();
            sh[threadIdx.x] += t;
            __syncthreads();
        }
        const int excl = carry + sh[threadIdx.x] - v;
        if (i < NC) {
            foff[i] = excl;
            fcur[i] = excl;
            gb[i] = v ? atomicAdd(&ccur[i], v) : 0;
        }
        __syncthreads();
        if (threadIdx.x == 255) carry += sh[255];
        __syncthreads();
    }

    for (int t = 0; t < CHUNK / 256; ++t) {
        const int k = t * 256 + threadIdx.x;
        if (k < n) {
            int c; unsigned ent;
            edge_cd(srcp, dstp, base + k, &c, &ent);
            const int p = atomicAdd(&fcur[c], 1);
            outE[p] = ent;
            binof[p] = (unsigned short)c;
        }
    }
    __syncthreads();

    for (int i = threadIdx.x; i < n; i += 256) {
        const int c = binof[i];
        staging[gb[c] + (i - foff[c])] = outE[i];
    }
}

// ---------------- fine sort (vul buckets) (proven) ----------------
__global__ __launch_bounds__(256)
void fine_sort_vul(const unsigned* __restrict__ staging,
                   const int* __restrict__ cbase, const int* __restrict__ ccnt,
                   int* __restrict__ srcs, int* __restrict__ offs)
{
    __shared__ unsigned raw[VCAP];
    __shared__ int srt[VCAP];
    __shared__ int foff[1025];
    __shared__ int fcur[1024];
    __shared__ int sh[256];
    __shared__ int carry;

    const int c = blockIdx.x;
    const int nb = min(ccnt[c], VCAP);
    const int gb = cbase[c];
    const int tid = threadIdx.x;

    for (int i = tid; i < 1024; i += 256) fcur[i] = 0;
    if (tid == 0) carry = 0;
    __syncthreads();
    for (int i = tid; i < nb; i += 256) {
        unsigned e = staging[gb + i];
        raw[i] = e;
        atomicAdd(&fcur[e >> 17], 1);
    }
    __syncthreads();
    for (int b = 0; b < 1024; b += 256) {
        const int i = b + tid;
        const int v = fcur[i];
        sh[tid] = v;
        __syncthreads();
        for (int st = 1; st < 256; st <<= 1) {
            int t = (tid >= st) ? sh[tid - st] : 0;
            __syncthreads();
            sh[tid] += t;
            __syncthreads();
        }
        foff[i] = carry + sh[tid] - v;
        __syncthreads();
        if (tid == 255) carry += sh[255];
        __syncthreads();
    }
    __syncthreads();
    for (int i = tid; i < 1024; i += 256) fcur[i] = foff[i];
    __syncthreads();
    for (int i = tid; i < nb; i += 256) {
        unsigned e = raw[i];
        const int p = atomicAdd(&fcur[e >> 17], 1);
        srt[p] = (int)(e & 0x1FFFFu);
    }
    __syncthreads();
    for (int i = tid; i < nb; i += 256) srcs[gb + i] = srt[i];
    for (int lk = tid; lk < 1024; lk += 256) {
        const int d = c * 256 + (lk >> 2);
        if (d < N_VUL) offs[c * 1024 + lk] = gb + foff[lk];
    }
}

// ---------------- fine sort (oth buckets) (proven) ----------------
__global__ __launch_bounds__(256)
void fine_sort_oth(const unsigned* __restrict__ staging,
                   const int* __restrict__ cbase, const int* __restrict__ ccnt,
                   int* __restrict__ srcs, int* __restrict__ offs)
{
    __shared__ unsigned raw[OCAP];
    __shared__ int srt[OCAP];
    __shared__ int foff[257];
    __shared__ int fcur[256];
    __shared__ int sh[256];

    const int co = blockIdx.x;
    const int j = co / NCO_J, dg = co - j * NCO_J;
    const int c = NCV + co;
    const int nb = min(ccnt[c], OCAP);
    const int gb = cbase[c];
    const int tid = threadIdx.x;

    fcur[tid] = 0;
    __syncthreads();
    for (int i = tid; i < nb; i += 256) {
        unsigned e = staging[gb + i];
        raw[i] = e;
        atomicAdd(&fcur[e >> 17], 1);
    }
    __syncthreads();
    {
        const int v = fcur[tid];
        sh[tid] = v;
        __syncthreads();
        for (int st = 1; st < 256; st <<= 1) {
            int t = (tid >= st) ? sh[tid - st] : 0;
            __syncthreads();
            sh[tid] += t;
            __syncthreads();
        }
        foff[tid] = sh[tid] - v;
        if (tid == 255) foff[256] = sh[255];
        __syncthreads();
        fcur[tid] = foff[tid];
    }
    __syncthreads();
    for (int i = tid; i < nb; i += 256) {
        unsigned e = raw[i];
        const int p = atomicAdd(&fcur[e >> 17], 1);
        srt[p] = (int)(e & 0x1FFFFu);
    }
    __syncthreads();
    for (int i = tid; i < nb; i += 256) srcs[gb + i] = srt[i];
    {
        const int d = dg * 256 + tid;
        if (d < N_OTH) offs[VKEYS + j * N_OTH + d] = gb + foff[tid];
    }
}

// ---------------- merged gather: vul blocks [0,NVB), oth blocks [NVB,NVB+N_OTH) ----------------
__global__ __launch_bounds__(256)
void fused_gather(const int* __restrict__ srcs, const int* __restrict__ offs,
                  const unsigned short* __restrict__ othTab,
                  const unsigned short* __restrict__ vulTab,
                  const float* __restrict__ rinHrS,
                  const float* __restrict__ rinHrB,
                  const float* __restrict__ rinHtVul,
                  const float* __restrict__ rinHtOth,
                  float* __restrict__ out)
{
    const int lane = threadIdx.x & 63;
    const int g = lane >> 4, l = lane & 15;

    if ((int)blockIdx.x < NVB) {
        // ---------- vul path (r7/r9-proven) ----------
        const int d = blockIdx.x * 4 + (threadIdx.x >> 6);
        const float* hrow = out + (size_t)d * 256 + l * 8;
        float b0[8];
        {
            float4 t0 = *(const float4*)(hrow);
            float4 t1 = *(const float4*)(hrow + 4);
            b0[0] = t0.x; b0[1] = t0.y; b0[2] = t0.z; b0[3] = t0.w;
            b0[4] = t1.x; b0[5] = t1.y; b0[6] = t1.z; b0[7] = t1.w;
        }
        const float rnb = rinHtVul[d];

        float acc[4][8];
        float ss[4];
        #pragma unroll
        for (int et = 0; et < 4; ++et) {
            ss[et] = 0.f;
            #pragma unroll
            for (int j = 0; j < 8; ++j) acc[et][j] = 0.f;
        }
        #pragma unroll
        for (int et = 0; et < 4; ++et) {
            const unsigned short* T = othTab + (size_t)et * NO128;
            const float* rA = rinHrS + (size_t)et * N_OTH;
            const int k0 = offs[d * 4 + et], k1 = offs[d * 4 + et + 1];
            for (int p0 = k0; p0 < k1; p0 += 4) {
                const int p = p0 + g;
                const bool ok = (p < k1);
                const int s = srcs[ok ? p : k0];
                bf16x8 av = *(const bf16x8*)(T + (size_t)s * 128 + l * 8);
                float a[8];
                #pragma unroll
                for (int j = 0; j < 8; ++j) a[j] = b2f((unsigned short)av[j]);
                float dp = 0.f;
                #pragma unroll
                for (int j = 0; j < 8; ++j) dp = fmaf(a[j], b0[j], dp);
                dp += __shfl_xor(dp, 1); dp += __shfl_xor(dp, 2);
                dp += __shfl_xor(dp, 4); dp += __shfl_xor(dp, 8);
                const float v = ok ? dp * rA[s] * rnb : 0.f;
                ss[et] += v;
                #pragma unroll
                for (int j = 0; j < 8; ++j) acc[et][j] = fmaf(v, a[j], acc[et][j]);
            }
        }
        #pragma unroll
        for (int et = 0; et < 4; ++et) {
            float t = ss[et];
            t += __shfl_xor(t, 16); t += __shfl_xor(t, 32);
            ss[et] = t;
        }
        const int o0 = offs[d * 4], o1 = offs[d * 4 + 1], o2 = offs[d * 4 + 2],
                  o3 = offs[d * 4 + 3], o4 = offs[d * 4 + 4];
        const float m0 = ss[0] / fmaxf((float)(o1 - o0), 1.f);
        const float m1 = ss[1] / fmaxf((float)(o2 - o1), 1.f);
        const float m2 = ss[2] / fmaxf((float)(o3 - o2), 1.f);
        const float m3 = ss[3] / fmaxf((float)(o4 - o3), 1.f);
        const float e0 = expf(m0), e1 = expf(m1), e2 = expf(m2), e3 = expf(m3);
        const float wp = 0.6f / (e0 + e1), wn = 0.4f / (e2 + e3);
        const float w0 = e0 * wp, w1 = e1 * wp, w2 = e2 * wn, w3 = e3 * wn;

        float res[8];
        #pragma unroll
        for (int j = 0; j < 8; ++j) {
            float t = w0 * acc[0][j] + w1 * acc[1][j] + w2 * acc[2][j] + w3 * acc[3][j];
            t += __shfl_xor(t, 16); t += __shfl_xor(t, 32);
            res[j] = t;
        }
        if (g == 0) {
            float4 r0 = {res[0], res[1], res[2], res[3]};
            float4 r1 = {res[4], res[5], res[6], res[7]};
            float* o = out + (size_t)d * 256 + 128 + l * 8;
            *(float4*)(o) = r0;
            *(float4*)(o + 4) = r1;
        }
    } else {
        // ---------- oth path, unrolled x2 ----------
        float* outO = out + (size_t)N_VUL * 256;
        const int j = threadIdx.x >> 6;
        const int d = blockIdx.x - NVB;

        const float* hrow = outO + ((size_t)j * N_OTH + d) * 256 + l * 8;
        float b0[8];
        {
            float4 t0 = *(const float4*)(hrow);
            float4 t1 = *(const float4*)(hrow + 4);
            b0[0] = t0.x; b0[1] = t0.y; b0[2] = t0.z; b0[3] = t0.w;
            b0[4] = t1.x; b0[5] = t1.y; b0[6] = t1.z; b0[7] = t1.w;
        }
        const float rnb = rinHtOth[j * N_OTH + d];
        const unsigned short* A = vulTab + (size_t)j * NV128;
        const unsigned short* M = vulTab + (size_t)3 * NV128;   // hr_final[0] = We[7] proj
        const float* rA = rinHrB + (size_t)j * N_VUL;

        const int key = VKEYS + j * N_OTH + d;
        const int k0 = offs[key], k1 = offs[key + 1];

        float acc[8];
        #pragma unroll
        for (int jj = 0; jj < 8; ++jj) acc[jj] = 0.f;

        for (int p0 = k0; p0 < k1; p0 += 8) {
            const int pa = p0 + g, pb = p0 + 4 + g;
            const bool oka = (pa < k1), okb = (pb < k1);
            const int sa = srcs[oka ? pa : k0];
            const int sb = srcs[okb ? pb : k0];
            bf16x8 ava = *(const bf16x8*)(A + (size_t)sa * 128 + l * 8);
            bf16x8 avb = *(const bf16x8*)(A + (size_t)sb * 128 + l * 8);
            float aa[8], ab[8];
            #pragma unroll
            for (int jj = 0; jj < 8; ++jj) {
                aa[jj] = b2f((unsigned short)ava[jj]);
                ab[jj] = b2f((unsigned short)avb[jj]);
            }
            float dpa = 0.f, dpb = 0.f;
            #pragma unroll
            for (int jj = 0; jj < 8; ++jj) {
                dpa = fmaf(aa[jj], b0[jj], dpa);
                dpb = fmaf(ab[jj], b0[jj], dpb);
            }
            dpa += __shfl_xor(dpa, 1); dpb += __shfl_xor(dpb, 1);
            dpa += __shfl_xor(dpa, 2); dpb += __shfl_xor(dpb, 2);
            dpa += __shfl_xor(dpa, 4); dpb += __shfl_xor(dpb, 4);
            dpa += __shfl_xor(dpa, 8); dpb += __shfl_xor(dpb, 8);
            const float va = oka ? dpa * rA[sa] * rnb : 0.f;
            const float vb = okb ? dpb * rA[sb] * rnb : 0.f;
            if (j == 3) {
                #pragma unroll
                for (int jj = 0; jj < 8; ++jj)
                    acc[jj] = fmaf(vb, ab[jj], fmaf(va, aa[jj], acc[jj]));
            } else {
                bf16x8 mva = *(const bf16x8*)(M + (size_t)sa * 128 + l * 8);
                bf16x8 mvb = *(const bf16x8*)(M + (size_t)sb * 128 + l * 8);
                #pragma unroll
                for (int jj = 0; jj < 8; ++jj)
                    acc[jj] = fmaf(vb, b2f((unsigned short)mvb[jj]),
                                   fmaf(va, b2f((unsigned short)mva[jj]), acc[jj]));
            }
        }
        #pragma unroll
        for (int jj = 0; jj < 8; ++jj) {
            float t = acc[jj];
            t += __shfl_xor(t, 16); t += __shfl_xor(t, 32);
            acc[jj] = t;
        }
        if (g == 0) {
            float4 r0 = {acc[0], acc[1], acc[2], acc[3]};
            float4 r1 = {acc[4], acc[5], acc[6], acc[7]};
            float* o = outO + ((size_t)j * N_OTH + d) * 256 + 128 + l * 8;
            *(float4*)(o) = r0;
            *(float4*)(o + 4) = r1;
        }
    }
}

extern "C" void kernel_launch(void* const* d_in, const int* in_sizes, int n_in,
                              void* d_out, int out_size, void* d_ws, size_t ws_size,
                              hipStream_t stream)
{
    // ---- size-based input resolution (proven) ----
    int i_fv = 0, i_fo = 1, i_We = 2, i_Wn = 3, i_bn = 4, i_iA = 5, i_iB = 6;
    {
        int a = -1, b = -1;
        for (int i = 0; i < n_in; ++i) {
            switch (in_sizes[i]) {
                case 25600000: i_fv = i; break;
                case 20480000: i_fo = i; break;
                case   262144: i_We = i; break;
                case   163840: i_Wn = i; break;
                case      640: i_bn = i; break;
                case  3200000: if (a < 0) a = i; else b = i; break;
                default: break;
            }
        }
        if (a >= 0 && b >= 0) { i_iA = a; i_iB = b; }
    }
    const float* feat_vul = (const float*)d_in[i_fv];
    const float* feat_oth = (const float*)d_in[i_fo];
    const float* We = (const float*)d_in[i_We];
    const float* Wn = (const float*)d_in[i_Wn];
    const float* bn = (const float*)d_in[i_bn];
    const int* idxA = (const int*)d_in[i_iA];
    const int* idxB = (const int*)d_in[i_iB];
    float* out = (float*)d_out;

    // ---- workspace carve (~150 MB) ----
    int*      flag    = (int*)d_ws;                       // 4 (zeroed)
    int*      ccnt    = flag + 4;                         // NC (zeroed)
    int*      cbase   = ccnt + NC;                        // NC
    int*      ccur    = cbase + NC;                       // NC
    unsigned* staging = (unsigned*)(ccur + NC);           // TOT_E
    int*      srcs    = (int*)(staging + TOT_E);          // TOT_E
    int*      offs    = srcs + TOT_E;                     // KEYS+1
    float*    rinHtVul = (float*)(offs + KEYS + 1);       // N_VUL
    float*    rinHtOth = rinHtVul + N_VUL;                // 4*N_OTH
    float*    rinHrB   = rinHtOth + (size_t)4 * N_OTH;    // 4*N_VUL
    float*    rinHrS   = rinHrB + (size_t)4 * N_VUL;      // 4*N_OTH
    unsigned short* vulTab = (unsigned short*)(rinHrS + (size_t)4 * N_OTH); // 4*NV128
    unsigned short* othTab = vulTab + 4 * NV128;          // 4*NO128
    unsigned short* Wb     = othTab + 4 * NO128;          // 13*32768

    hipMemsetAsync(d_ws, 0, (4 + (size_t)NC) * sizeof(int), stream);

    probe_idx<<<(E_NUM + 255) / 256, 256, 0, stream>>>(idxA, flag);
    pack_w<<<(13 * 32768 + 255) / 256, 256, 0, stream>>>(We, Wn, Wb);

    const size_t OUT0 = (size_t)N_VUL * 256;

    // projections (with fused row norms): vul -> ht+hrB0..3; oth i -> ht_i+hrS_i
    proj_mfma<<<(N_VUL + 63) / 64, 256, 0, stream>>>(
        feat_vul, Wb, bn, out, vulTab, 5, N_VUL, rinHtVul, rinHrB);
    for (int i = 0; i < 4; ++i)
        proj_mfma<<<(N_OTH + 63) / 64, 256, 0, stream>>>(
            feat_oth + (size_t)i * N_OTH * K_DIM,
            Wb + (size_t)(5 + 2 * i) * 32768,
            bn + (size_t)(i + 1) * D_OUT,
            out + OUT0 + (size_t)i * N_OTH * 256,
            othTab + (size_t)i * NO128, 2, N_OTH,
            rinHtOth + (size_t)i * N_OTH, rinHrS + (size_t)i * N_OTH);

    // coarse-bucketed coalesced staging, then per-bucket LDS fine sort -> global CSR
    chist<<<(TOT_E + 16383) / 16384, 256, 0, stream>>>(idxA, idxB, flag, ccnt);
    cscan<<<1, 256, 0, stream>>>(ccnt, cbase, ccur, offs);
    cstage<<<(TOT_E + CHUNK - 1) / CHUNK, 256, 0, stream>>>(idxA, idxB, flag, ccur, staging);
    fine_sort_vul<<<NCV, 256, 0, stream>>>(staging, cbase, ccnt, srcs, offs);
    fine_sort_oth<<<4 * NCO_J, 256, 0, stream>>>(staging, cbase, ccnt, srcs, offs);

    // merged high-occupancy gathers
    fused_gather<<<NVB + N_OTH, 256, 0, stream>>>(
        srcs, offs, othTab, vulTab, rinHrS, rinHrB, rinHtVul, rinHtOth, out);
}

// Round 11
// 824.626 us; speedup vs baseline: 1.1527x; 1.1527x over previous
//
#include <hip/hip_runtime.h>

#define N_VUL 100000
#define N_OTH 20000
#define E_NUM 400000
#define K_DIM 256
#define D_OUT 128
#define EPS 1e-8f
#define LDW 264   // padded LDS row (bf16 elems)

#define NCV 391               // ceil(N_VUL/256) coarse buckets (vul side)
#define NCO_J 79              // ceil(N_OTH/256) per etype j (oth side)
#define NC (NCV + 4 * NCO_J)  // 707 total coarse buckets
#define TOT_E (8 * E_NUM)     // 3,200,000 edges
#define CHUNK 8192            // edges per cstage block
#define VCAP 5120             // max edges per vul bucket
#define OCAP 6144             // max edges per oth bucket
#define VKEYS (4 * N_VUL)
#define KEYS  (4 * N_VUL + 4 * N_OTH)

typedef __attribute__((ext_vector_type(8))) short bf16x8;
typedef __attribute__((ext_vector_type(4))) float f32x4;

static const size_t NV128 = (size_t)N_VUL * 128;
static const size_t NO128 = (size_t)N_OTH * 128;

__device__ __forceinline__ unsigned short f2b(float f) {
    unsigned int u = __float_as_uint(f);
    u += 0x7FFFu + ((u >> 16) & 1u);
    return (unsigned short)(u >> 16);
}
__device__ __forceinline__ float b2f(unsigned short h) {
    return __uint_as_float(((unsigned int)h) << 16);
}

// ---------------- src/dst disambiguation probe (proven) ----------------
__global__ __launch_bounds__(256)
void probe_idx(const int* __restrict__ cand, int* __restrict__ flag)
{
    const int e = blockIdx.x * 256 + threadIdx.x;
    if (e >= E_NUM) return;
    int v = cand[e];
    if (v < 0 || v >= N_OTH) atomicOr(flag, 1);
}

// ---------------- weight pack (proven) ----------------
// order: 0=Wn0, 1..4=We4..7, 5=Wn1,6=We0, 7=Wn2,8=We1, 9=Wn3,10=We2, 11=Wn4,12=We3
__global__ __launch_bounds__(256)
void pack_w(const float* __restrict__ We, const float* __restrict__ Wn,
            unsigned short* __restrict__ Wb)
{
    const int id = blockIdx.x * 256 + threadIdx.x;
    if (id >= 13 * 32768) return;
    const int wp = id >> 15;
    const int n  = (id >> 8) & 127;
    const int k  = id & 255;
    const float* S;
    if (wp == 0)      S = Wn;
    else if (wp <= 4) S = We + (size_t)(3 + wp) * 32768;
    else if (wp & 1)  S = Wn + (size_t)((wp - 3) >> 1) * 32768;
    else              S = We + (size_t)((wp - 6) >> 1) * 32768;
    Wb[id] = f2b(S[k * D_OUT + n]);
}

// ---------------- fused MFMA projection (r5/r9-proven; generalized table layout) ----------------
// w==0 -> f32 ht (+bias) into outF (ld 256)
// w>0  -> bf16 at tabs[row*nodeStride + (w-1)*wStride + col]
__global__ __launch_bounds__(256)
void proj_mfma(const float* __restrict__ X, const unsigned short* __restrict__ Wb,
               const float* __restrict__ bias, float* __restrict__ outF,
               unsigned short* __restrict__ tabs, int NW, int N,
               int nodeStride, int wStride)
{
    __shared__ unsigned short xs[64 * LDW];
    const int tid  = threadIdx.x;
    const int wave = tid >> 6, lane = tid & 63;
    const int r0   = blockIdx.x * 64;

    #pragma unroll
    for (int c = 0; c < 16; ++c) {
        int f = c * 256 + tid;
        int row = f >> 6, col4 = f & 63;
        int gr = r0 + row; if (gr >= N) gr = N - 1;
        float4 v = *(const float4*)(X + (size_t)gr * K_DIM + col4 * 4);
        unsigned short* p = xs + row * LDW + col4 * 4;
        p[0] = f2b(v.x); p[1] = f2b(v.y); p[2] = f2b(v.z); p[3] = f2b(v.w);
    }
    __syncthreads();

    const int n0   = wave * 32;
    const int arow = lane & 15, akd = (lane >> 4) * 8;
    const int bcol = lane & 15, bkd = (lane >> 4) * 8;
    const int rsub = (lane >> 4) * 4;

    float bias0 = 0.f, bias1 = 0.f;
    if (bias) { bias0 = bias[n0 + bcol]; bias1 = bias[n0 + 16 + bcol]; }

    for (int w = 0; w < NW; ++w) {
        f32x4 acc[4][2];
        #pragma unroll
        for (int m = 0; m < 4; ++m) {
            acc[m][0] = (f32x4){0.f, 0.f, 0.f, 0.f};
            acc[m][1] = (f32x4){0.f, 0.f, 0.f, 0.f};
        }
        const unsigned short* wb = Wb + (size_t)w * 128 * 256;
        #pragma unroll
        for (int k = 0; k < 8; ++k) {
            bf16x8 b0 = *(const bf16x8*)(wb + (size_t)(n0 + bcol) * 256 + k * 32 + bkd);
            bf16x8 b1 = *(const bf16x8*)(wb + (size_t)(n0 + 16 + bcol) * 256 + k * 32 + bkd);
            #pragma unroll
            for (int m = 0; m < 4; ++m) {
                bf16x8 a = *(const bf16x8*)(xs + (m * 16 + arow) * LDW + k * 32 + akd);
                acc[m][0] = __builtin_amdgcn_mfma_f32_16x16x32_bf16(a, b0, acc[m][0], 0, 0, 0);
                acc[m][1] = __builtin_amdgcn_mfma_f32_16x16x32_bf16(a, b1, acc[m][1], 0, 0, 0);
            }
        }
        if (w == 0) {
            #pragma unroll
            for (int m = 0; m < 4; ++m)
                #pragma unroll
                for (int nn = 0; nn < 2; ++nn) {
                    const int col = n0 + nn * 16 + bcol;
                    const float bb = nn ? bias1 : bias0;
                    #pragma unroll
                    for (int j = 0; j < 4; ++j) {
                        const int row = r0 + m * 16 + rsub + j;
                        if (row < N) outF[(size_t)row * 256 + col] = acc[m][nn][j] + bb;
                    }
                }
        } else {
            unsigned short* tw = tabs + (size_t)(w - 1) * wStride;
            #pragma unroll
            for (int m = 0; m < 4; ++m)
                #pragma unroll
                for (int nn = 0; nn < 2; ++nn) {
                    const int col = n0 + nn * 16 + bcol;
                    #pragma unroll
                    for (int j = 0; j < 4; ++j) {
                        const int row = r0 + m * 16 + rsub + j;
                        if (row < N) tw[(size_t)row * nodeStride + col] = f2b(acc[m][nn][j]);
                    }
                }
        }
    }
}

// ---------------- reciprocal row L2 norms (r9-proven) ----------------
__global__ __launch_bounds__(256)
void rownorm_f(const float* __restrict__ T, float* __restrict__ rn, int N)
{
    const int lr = threadIdx.x >> 6;
    const int l  = threadIdx.x & 63;
    const int r  = blockIdx.x * 4 + lr;
    if (r >= N) return;
    float a = T[(size_t)r * 256 + l];
    float b = T[(size_t)r * 256 + 64 + l];
    float s = a * a + b * b;
    #pragma unroll
    for (int m = 32; m; m >>= 1) s += __shfl_xor(s, m);
    if (l == 0) rn[r] = 1.f / fmaxf(sqrtf(s), EPS);
}

// contiguous bf16 table, ld 128 (othTab)
__global__ __launch_bounds__(256)
void rownorm_b(const unsigned short* __restrict__ T, float* __restrict__ rn, int N)
{
    const int lr = threadIdx.x >> 6;
    const int l  = threadIdx.x & 63;
    const int r  = blockIdx.x * 4 + lr;
    if (r >= N) return;
    float a = b2f(T[(size_t)r * D_OUT + l]);
    float b = b2f(T[(size_t)r * D_OUT + 64 + l]);
    float s = a * a + b * b;
    #pragma unroll
    for (int m = 32; m; m >>= 1) s += __shfl_xor(s, m);
    if (l == 0) rn[r] = 1.f / fmaxf(sqrtf(s), EPS);
}

// interleaved vulTab [s][4][128]: row g in [0,4N): s=g>>2, w=g&3 -> rn[w*N+s]
__global__ __launch_bounds__(256)
void rownorm_bi(const unsigned short* __restrict__ T, float* __restrict__ rn, int N)
{
    const int lr = threadIdx.x >> 6;
    const int l  = threadIdx.x & 63;
    const int g  = blockIdx.x * 4 + lr;
    if (g >= 4 * N) return;
    const int s = g >> 2, w = g & 3;
    const unsigned short* row = T + (size_t)s * 512 + w * 128;
    float a = b2f(row[l]);
    float b = b2f(row[64 + l]);
    float ss = a * a + b * b;
    #pragma unroll
    for (int m = 32; m; m >>= 1) ss += __shfl_xor(ss, m);
    if (l == 0) rn[(size_t)w * N + s] = 1.f / fmaxf(sqrtf(ss), EPS);
}

// ---------------- edge -> (coarse bucket, packed entry) (proven) ----------------
__device__ __forceinline__ void edge_cd(const int* __restrict__ srcp,
                                        const int* __restrict__ dstp,
                                        int id, int* c_out, unsigned* entry_out)
{
    const int et = id / E_NUM;
    const int e  = id - et * E_NUM;
    int d = dstp[(size_t)et * E_NUM + e];
    if (et < 4) {
        d = d < 0 ? 0 : (d >= N_VUL ? N_VUL - 1 : d);
        *c_out = d >> 8;
        if (entry_out) {
            int s = srcp[(size_t)et * E_NUM + e];
            s = s < 0 ? 0 : (s >= N_OTH ? N_OTH - 1 : s);
            *entry_out = ((unsigned)(((d & 255) << 2) | et) << 17) | (unsigned)s;
        }
    } else {
        d = d < 0 ? 0 : (d >= N_OTH ? N_OTH - 1 : d);
        *c_out = NCV + (et - 4) * NCO_J + (d >> 8);
        if (entry_out) {
            int s = srcp[(size_t)et * E_NUM + e];
            s = s < 0 ? 0 : (s >= N_VUL ? N_VUL - 1 : s);
            *entry_out = ((unsigned)(d & 255) << 17) | (unsigned)s;
        }
    }
}

// ---------------- coarse histogram (proven) ----------------
__global__ __launch_bounds__(256)
void chist(const int* __restrict__ pA, const int* __restrict__ pB,
           const int* __restrict__ flag, int* __restrict__ ccnt)
{
    __shared__ int h[NC];
    for (int i = threadIdx.x; i < NC; i += 256) h[i] = 0;
    __syncthreads();
    const int flagv = *flag;
    const int* srcp = flagv ? pB : pA;
    const int* dstp = flagv ? pA : pB;
    const int base = blockIdx.x * 16384;
    for (int t = 0; t < 64; ++t) {
        const int id = base + t * 256 + threadIdx.x;
        if (id < TOT_E) {
            int c; edge_cd(srcp, dstp, id, &c, nullptr);
            atomicAdd(&h[c], 1);
        }
    }
    __syncthreads();
    for (int i = threadIdx.x; i < NC; i += 256)
        if (h[i]) atomicAdd(&ccnt[i], h[i]);
}

// ---------------- exclusive scan of coarse counts; writes offs[KEYS] ----------------
__global__ __launch_bounds__(256)
void cscan(const int* __restrict__ ccnt, int* __restrict__ cbase,
           int* __restrict__ ccur, int* __restrict__ offs)
{
    __shared__ int sh[256];
    __shared__ int carry;
    if (threadIdx.x == 0) carry = 0;
    __syncthreads();
    for (int b = 0; b < NC; b += 256) {
        const int i = b + threadIdx.x;
        const int v = (i < NC) ? ccnt[i] : 0;
        sh[threadIdx.x] = v;
        __syncthreads();
        for (int st = 1; st < 256; st <<= 1) {
            int t = (threadIdx.x >= st) ? sh[threadIdx.x - st] : 0;
            __syncthreads();
            sh[threadIdx.x] += t;
            __syncthreads();
        }
        const int excl = carry + sh[threadIdx.x] - v;
        if (i < NC) { cbase[i] = excl; ccur[i] = excl; }
        __syncthreads();
        if (threadIdx.x == 255) carry += sh[255];
        __syncthreads();
    }
    if (threadIdx.x == 0) offs[KEYS] = carry;   // == TOT_E
}

// ---------------- staged scatter (proven) ----------------
__global__ __launch_bounds__(256)
void cstage(const int* __restrict__ pA, const int* __restrict__ pB,
            const int* __restrict__ flag, int* __restrict__ ccur,
            unsigned* __restrict__ staging)
{
    __shared__ unsigned outE[CHUNK];
    __shared__ unsigned short binof[CHUNK];
    __shared__ int foff[NC];
    __shared__ int fcur[NC];
    __shared__ int gb[NC];
    __shared__ int sh[256];
    __shared__ int carry;

    const int flagv = *flag;
    const int* srcp = flagv ? pB : pA;
    const int* dstp = flagv ? pA : pB;
    const int base = blockIdx.x * CHUNK;
    const int n = (base + CHUNK <= TOT_E) ? CHUNK : (TOT_E - base);

    for (int i = threadIdx.x; i < NC; i += 256) foff[i] = 0;
    if (threadIdx.x == 0) carry = 0;
    __syncthreads();

    for (int t = 0; t < CHUNK / 256; ++t) {
        const int k = t * 256 + threadIdx.x;
        if (k < n) {
            int c; edge_cd(srcp, dstp, base + k, &c, nullptr);
            atomicAdd(&foff[c], 1);
        }
    }
    __syncthreads();

    for (int b = 0; b < NC; b += 256) {
        const int i = b + threadIdx.x;
        const int v = (i < NC) ? foff[i] : 0;
        sh[threadIdx.x] = v;
        __syncthreads();
        for (int st = 1; st < 256; st <<= 1) {
            int t = (threadIdx.x >= st) ? sh[threadIdx.x - st] : 0;
            __syncthreads();
            sh[threadIdx.x] += t;
            __syncthreads();
        }
        const int excl = carry + sh[threadIdx.x] - v;
        if (i < NC) {
            foff[i] = excl;
            fcur[i] = excl;
            gb[i] = v ? atomicAdd(&ccur[i], v) : 0;
        }
        __syncthreads();
        if (threadIdx.x == 255) carry += sh[255];
        __syncthreads();
    }

    for (int t = 0; t < CHUNK / 256; ++t) {
        const int k = t * 256 + threadIdx.x;
        if (k < n) {
            int c; unsigned ent;
            edge_cd(srcp, dstp, base + k, &c, &ent);
            const int p = atomicAdd(&fcur[c], 1);
            outE[p] = ent;
            binof[p] = (unsigned short)c;
        }
    }
    __syncthreads();

    for (int i = threadIdx.x; i < n; i += 256) {
        const int c = binof[i];
        staging[gb[c] + (i - foff[c])] = outE[i];
    }
}

// ---------------- fine sort (vul buckets) (proven) ----------------
__global__ __launch_bounds__(256)
void fine_sort_vul(const unsigned* __restrict__ staging,
                   const int* __restrict__ cbase, const int* __restrict__ ccnt,
                   int* __restrict__ srcs, int* __restrict__ offs)
{
    __shared__ unsigned raw[VCAP];
    __shared__ int srt[VCAP];
    __shared__ int foff[1025];
    __shared__ int fcur[1024];
    __shared__ int sh[256];
    __shared__ int carry;

    const int c = blockIdx.x;
    const int nb = min(ccnt[c], VCAP);
    const int gb = cbase[c];
    const int tid = threadIdx.x;

    for (int i = tid; i < 1024; i += 256) fcur[i] = 0;
    if (tid == 0) carry = 0;
    __syncthreads();
    for (int i = tid; i < nb; i += 256) {
        unsigned e = staging[gb + i];
        raw[i] = e;
        atomicAdd(&fcur[e >> 17], 1);
    }
    __syncthreads();
    for (int b = 0; b < 1024; b += 256) {
        const int i = b + tid;
        const int v = fcur[i];
        sh[tid] = v;
        __syncthreads();
        for (int st = 1; st < 256; st <<= 1) {
            int t = (tid >= st) ? sh[tid - st] : 0;
            __syncthreads();
            sh[tid] += t;
            __syncthreads();
        }
        foff[i] = carry + sh[tid] - v;
        __syncthreads();
        if (tid == 255) carry += sh[255];
        __syncthreads();
    }
    __syncthreads();
    for (int i = tid; i < 1024; i += 256) fcur[i] = foff[i];
    __syncthreads();
    for (int i = tid; i < nb; i += 256) {
        unsigned e = raw[i];
        const int p = atomicAdd(&fcur[e >> 17], 1);
        srt[p] = (int)(e & 0x1FFFFu);
    }
    __syncthreads();
    for (int i = tid; i < nb; i += 256) srcs[gb + i] = srt[i];
    for (int lk = tid; lk < 1024; lk += 256) {
        const int d = c * 256 + (lk >> 2);
        if (d < N_VUL) offs[c * 1024 + lk] = gb + foff[lk];
    }
}

// ---------------- fine sort (oth buckets) (proven) ----------------
__global__ __launch_bounds__(256)
void fine_sort_oth(const unsigned* __restrict__ staging,
                   const int* __restrict__ cbase, const int* __restrict__ ccnt,
                   int* __restrict__ srcs, int* __restrict__ offs)
{
    __shared__ unsigned raw[OCAP];
    __shared__ int srt[OCAP];
    __shared__ int foff[257];
    __shared__ int fcur[256];
    __shared__ int sh[256];

    const int co = blockIdx.x;
    const int j = co / NCO_J, dg = co - j * NCO_J;
    const int c = NCV + co;
    const int nb = min(ccnt[c], OCAP);
    const int gb = cbase[c];
    const int tid = threadIdx.x;

    fcur[tid] = 0;
    __syncthreads();
    for (int i = tid; i < nb; i += 256) {
        unsigned e = staging[gb + i];
        raw[i] = e;
        atomicAdd(&fcur[e >> 17], 1);
    }
    __syncthreads();
    {
        const int v = fcur[tid];
        sh[tid] = v;
        __syncthreads();
        for (int st = 1; st < 256; st <<= 1) {
            int t = (tid >= st) ? sh[tid - st] : 0;
            __syncthreads();
            sh[tid] += t;
            __syncthreads();
        }
        foff[tid] = sh[tid] - v;
        if (tid == 255) foff[256] = sh[255];
        __syncthreads();
        fcur[tid] = foff[tid];
    }
    __syncthreads();
    for (int i = tid; i < nb; i += 256) {
        unsigned e = raw[i];
        const int p = atomicAdd(&fcur[e >> 17], 1);
        srt[p] = (int)(e & 0x1FFFFu);
    }
    __syncthreads();
    for (int i = tid; i < nb; i += 256) srcs[gb + i] = srt[i];
    {
        const int d = dg * 256 + tid;
        if (d < N_OTH) offs[VKEYS + j * N_OTH + d] = gb + foff[tid];
    }
}

// ---------------- vul aggregation (r7/r9-proven, high occupancy) ----------------
__global__ __launch_bounds__(256)
void vul_gather(const int* __restrict__ srcs, const int* __restrict__ offs,
                const unsigned short* __restrict__ othTab,
                const float* __restrict__ rinHrS,
                const float* __restrict__ rinHtVul,
                float* __restrict__ out)
{
    const int d = blockIdx.x * 4 + (threadIdx.x >> 6);
    const int lane = threadIdx.x & 63;
    const int g = lane >> 4, l = lane & 15;

    const float* hrow = out + (size_t)d * 256 + l * 8;
    float b0[8];
    {
        float4 t0 = *(const float4*)(hrow);
        float4 t1 = *(const float4*)(hrow + 4);
        b0[0] = t0.x; b0[1] = t0.y; b0[2] = t0.z; b0[3] = t0.w;
        b0[4] = t1.x; b0[5] = t1.y; b0[6] = t1.z; b0[7] = t1.w;
    }
    const float rnb = rinHtVul[d];

    float acc[4][8];
    float ss[4];
    #pragma unroll
    for (int et = 0; et < 4; ++et) {
        ss[et] = 0.f;
        #pragma unroll
        for (int j = 0; j < 8; ++j) acc[et][j] = 0.f;
    }

    #pragma unroll
    for (int et = 0; et < 4; ++et) {
        const unsigned short* T = othTab + (size_t)et * NO128;
        const float* rA = rinHrS + (size_t)et * N_OTH;
        const int k0 = offs[d * 4 + et], k1 = offs[d * 4 + et + 1];
        for (int p0 = k0; p0 < k1; p0 += 4) {
            const int p = p0 + g;
            const bool ok = (p < k1);
            const int s = srcs[ok ? p : k0];
            bf16x8 av = *(const bf16x8*)(T + (size_t)s * 128 + l * 8);
            float a[8];
            #pragma unroll
            for (int j = 0; j < 8; ++j) a[j] = b2f((unsigned short)av[j]);
            float dp = 0.f;
            #pragma unroll
            for (int j = 0; j < 8; ++j) dp = fmaf(a[j], b0[j], dp);
            dp += __shfl_xor(dp, 1); dp += __shfl_xor(dp, 2);
            dp += __shfl_xor(dp, 4); dp += __shfl_xor(dp, 8);
            const float v = ok ? dp * rA[s] * rnb : 0.f;
            ss[et] += v;
            #pragma unroll
            for (int j = 0; j < 8; ++j) acc[et][j] = fmaf(v, a[j], acc[et][j]);
        }
    }

    #pragma unroll
    for (int et = 0; et < 4; ++et) {
        float t = ss[et];
        t += __shfl_xor(t, 16); t += __shfl_xor(t, 32);
        ss[et] = t;
    }
    const int o0 = offs[d * 4], o1 = offs[d * 4 + 1], o2 = offs[d * 4 + 2],
              o3 = offs[d * 4 + 3], o4 = offs[d * 4 + 4];
    const float m0 = ss[0] / fmaxf((float)(o1 - o0), 1.f);
    const float m1 = ss[1] / fmaxf((float)(o2 - o1), 1.f);
    const float m2 = ss[2] / fmaxf((float)(o3 - o2), 1.f);
    const float m3 = ss[3] / fmaxf((float)(o4 - o3), 1.f);
    const float e0 = expf(m0), e1 = expf(m1), e2 = expf(m2), e3 = expf(m3);
    const float wp = 0.6f / (e0 + e1), wn = 0.4f / (e2 + e3);
    const float w0 = e0 * wp, w1 = e1 * wp, w2 = e2 * wn, w3 = e3 * wn;

    float res[8];
    #pragma unroll
    for (int j = 0; j < 8; ++j) {
        float t = w0 * acc[0][j] + w1 * acc[1][j] + w2 * acc[2][j] + w3 * acc[3][j];
        t += __shfl_xor(t, 16); t += __shfl_xor(t, 32);
        res[j] = t;
    }
    if (g == 0) {
        float4 r0 = {res[0], res[1], res[2], res[3]};
        float4 r1 = {res[4], res[5], res[6], res[7]};
        float* o = out + (size_t)d * 256 + 128 + l * 8;
        *(float4*)(o) = r0;
        *(float4*)(o + 4) = r1;
    }
}

// ---------------- oth aggregation (r9-proven; vulTab interleaved [s][4][128]) ----------------
__global__ __launch_bounds__(256)
void oth_gather(const int* __restrict__ srcs, const int* __restrict__ offs,
                const unsigned short* __restrict__ vulTab,   // [s][4][128]
                const float* __restrict__ rinHrB,
                const float* __restrict__ rinHtOth,
                float* __restrict__ outO)
{
    const int j = threadIdx.x >> 6;
    const int d = blockIdx.x;
    const int lane = threadIdx.x & 63;
    const int g = lane >> 4, l = lane & 15;

    const float* hrow = outO + ((size_t)j * N_OTH + d) * 256 + l * 8;
    float b0[8];
    {
        float4 t0 = *(const float4*)(hrow);
        float4 t1 = *(const float4*)(hrow + 4);
        b0[0] = t0.x; b0[1] = t0.y; b0[2] = t0.z; b0[3] = t0.w;
        b0[4] = t1.x; b0[5] = t1.y; b0[6] = t1.z; b0[7] = t1.w;
    }
    const float rnb = rinHtOth[j * N_OTH + d];
    const float* rA = rinHrB + (size_t)j * N_VUL;
    const int aOff = j * 128 + l * 8;         // score row (We[4+j] proj)
    const int mOff = 3 * 128 + l * 8;         // message row (We[7] proj = hr_final[0])

    const int key = VKEYS + j * N_OTH + d;
    const int k0 = offs[key], k1 = offs[key + 1];

    float acc[8];
    #pragma unroll
    for (int jj = 0; jj < 8; ++jj) acc[jj] = 0.f;

    for (int p0 = k0; p0 < k1; p0 += 4) {
        const int p = p0 + g;
        const bool ok = (p < k1);
        const int s = srcs[ok ? p : k0];
        const unsigned short* node = vulTab + (size_t)s * 512;
        bf16x8 av = *(const bf16x8*)(node + aOff);
        float a[8];
        #pragma unroll
        for (int jj = 0; jj < 8; ++jj) a[jj] = b2f((unsigned short)av[jj]);
        float dp = 0.f;
        #pragma unroll
        for (int jj = 0; jj < 8; ++jj) dp = fmaf(a[jj], b0[jj], dp);
        dp += __shfl_xor(dp, 1); dp += __shfl_xor(dp, 2);
        dp += __shfl_xor(dp, 4); dp += __shfl_xor(dp, 8);
        const float v = ok ? dp * rA[s] * rnb : 0.f;
        if (j == 3) {
            #pragma unroll
            for (int jj = 0; jj < 8; ++jj) acc[jj] = fmaf(v, a[jj], acc[jj]);
        } else {
            bf16x8 mv = *(const bf16x8*)(node + mOff);
            #pragma unroll
            for (int jj = 0; jj < 8; ++jj) acc[jj] = fmaf(v, b2f((unsigned short)mv[jj]), acc[jj]);
        }
    }

    #pragma unroll
    for (int jj = 0; jj < 8; ++jj) {
        float t = acc[jj];
        t += __shfl_xor(t, 16); t += __shfl_xor(t, 32);
        acc[jj] = t;
    }
    if (g == 0) {
        float4 r0 = {acc[0], acc[1], acc[2], acc[3]};
        float4 r1 = {acc[4], acc[5], acc[6], acc[7]};
        float* o = outO + ((size_t)j * N_OTH + d) * 256 + 128 + l * 8;
        *(float4*)(o) = r0;
        *(float4*)(o + 4) = r1;
    }
}

extern "C" void kernel_launch(void* const* d_in, const int* in_sizes, int n_in,
                              void* d_out, int out_size, void* d_ws, size_t ws_size,
                              hipStream_t stream)
{
    // ---- size-based input resolution (proven) ----
    int i_fv = 0, i_fo = 1, i_We = 2, i_Wn = 3, i_bn = 4, i_iA = 5, i_iB = 6;
    {
        int a = -1, b = -1;
        for (int i = 0; i < n_in; ++i) {
            switch (in_sizes[i]) {
                case 25600000: i_fv = i; break;
                case 20480000: i_fo = i; break;
                case   262144: i_We = i; break;
                case   163840: i_Wn = i; break;
                case      640: i_bn = i; break;
                case  3200000: if (a < 0) a = i; else b = i; break;
                default: break;
            }
        }
        if (a >= 0 && b >= 0) { i_iA = a; i_iB = b; }
    }
    const float* feat_vul = (const float*)d_in[i_fv];
    const float* feat_oth = (const float*)d_in[i_fo];
    const float* We = (const float*)d_in[i_We];
    const float* Wn = (const float*)d_in[i_Wn];
    const float* bn = (const float*)d_in[i_bn];
    const int* idxA = (const int*)d_in[i_iA];
    const int* idxB = (const int*)d_in[i_iB];
    float* out = (float*)d_out;

    // ---- workspace carve (~150 MB) ----
    int*      flag    = (int*)d_ws;                       // 4 (zeroed)
    int*      ccnt    = flag + 4;                         // NC (zeroed)
    int*      cbase   = ccnt + NC;                        // NC
    int*      ccur    = cbase + NC;                       // NC
    unsigned* staging = (unsigned*)(ccur + NC);           // TOT_E
    int*      srcs    = (int*)(staging + TOT_E);          // TOT_E
    int*      offs    = srcs + TOT_E;                     // KEYS+1
    float*    rinHtVul = (float*)(offs + KEYS + 1);       // N_VUL
    float*    rinHtOth = rinHtVul + N_VUL;                // 4*N_OTH
    float*    rinHrB   = rinHtOth + (size_t)4 * N_OTH;    // 4*N_VUL
    float*    rinHrS   = rinHrB + (size_t)4 * N_VUL;      // 4*N_OTH
    unsigned short* vulTab = (unsigned short*)(rinHrS + (size_t)4 * N_OTH); // 4*NV128 interleaved
    unsigned short* othTab = vulTab + 4 * NV128;          // 4*NO128
    unsigned short* Wb     = othTab + 4 * NO128;          // 13*32768

    hipMemsetAsync(d_ws, 0, (4 + (size_t)NC) * sizeof(int), stream);

    probe_idx<<<(E_NUM + 255) / 256, 256, 0, stream>>>(idxA, flag);
    pack_w<<<(13 * 32768 + 255) / 256, 256, 0, stream>>>(We, Wn, Wb);

    // CSR build FIRST (keeps projection outputs cache-warm for the gathers)
    chist<<<(TOT_E + 16383) / 16384, 256, 0, stream>>>(idxA, idxB, flag, ccnt);
    cscan<<<1, 256, 0, stream>>>(ccnt, cbase, ccur, offs);
    cstage<<<(TOT_E + CHUNK - 1) / CHUNK, 256, 0, stream>>>(idxA, idxB, flag, ccur, staging);
    fine_sort_vul<<<NCV, 256, 0, stream>>>(staging, cbase, ccnt, srcs, offs);
    fine_sort_oth<<<4 * NCO_J, 256, 0, stream>>>(staging, cbase, ccnt, srcs, offs);

    const size_t OUT0 = (size_t)N_VUL * 256;

    // projections: vul -> ht(f32) + interleaved hrB [s][4][128]; oth i -> ht_i + hrS_i (ld 128)
    proj_mfma<<<(N_VUL + 63) / 64, 256, 0, stream>>>(
        feat_vul, Wb, bn, out, vulTab, 5, N_VUL, 512, 128);
    for (int i = 0; i < 4; ++i)
        proj_mfma<<<(N_OTH + 63) / 64, 256, 0, stream>>>(
            feat_oth + (size_t)i * N_OTH * K_DIM,
            Wb + (size_t)(5 + 2 * i) * 32768,
            bn + (size_t)(i + 1) * D_OUT,
            out + OUT0 + (size_t)i * N_OTH * 256,
            othTab + (size_t)i * NO128, 2, N_OTH, 128, 0);

    // reciprocal norms
    rownorm_f<<<(N_VUL + 3) / 4, 256, 0, stream>>>(out, rinHtVul, N_VUL);
    rownorm_f<<<(4 * N_OTH + 3) / 4, 256, 0, stream>>>(out + OUT0, rinHtOth, 4 * N_OTH);
    rownorm_bi<<<(4 * N_VUL + 3) / 4, 256, 0, stream>>>(vulTab, rinHrB, N_VUL);
    rownorm_b<<<(4 * N_OTH + 3) / 4, 256, 0, stream>>>(othTab, rinHrS, 4 * N_OTH);

    // r9-proven high-occupancy gathers
    vul_gather<<<N_VUL / 4, 256, 0, stream>>>(srcs, offs, othTab, rinHrS, rinHtVul, out);
    oth_gather<<<N_OTH, 256, 0, stream>>>(srcs, offs, vulTab, rinHrB, rinHtOth, out + OUT0);
}

// Round 12
// 789.442 us; speedup vs baseline: 1.2041x; 1.0446x over previous
//
#include <hip/hip_runtime.h>

#define N_VUL 100000
#define N_OTH 20000
#define E_NUM 400000
#define K_DIM 256
#define D_OUT 128
#define EPS 1e-8f
#define LDW 264   // padded LDS row (bf16 elems)

#define NCV 391               // ceil(N_VUL/256) coarse buckets (vul side)
#define NCO_J 79              // ceil(N_OTH/256) per etype j (oth side)
#define NC (NCV + 4 * NCO_J)  // 707 total coarse buckets
#define TOT_E (8 * E_NUM)     // 3,200,000 edges
#define CHUNK 8192            // edges per cstage block
#define VCAP 5120             // max edges per vul bucket
#define OCAP 6144             // max edges per oth bucket
#define VKEYS (4 * N_VUL)
#define KEYS  (4 * N_VUL + 4 * N_OTH)

typedef __attribute__((ext_vector_type(8))) short bf16x8;
typedef __attribute__((ext_vector_type(4))) float f32x4;

static const size_t NV128 = (size_t)N_VUL * 128;
static const size_t NO128 = (size_t)N_OTH * 128;

__device__ __forceinline__ unsigned short f2b(float f) {
    unsigned int u = __float_as_uint(f);
    u += 0x7FFFu + ((u >> 16) & 1u);
    return (unsigned short)(u >> 16);
}
__device__ __forceinline__ float b2f(unsigned short h) {
    return __uint_as_float(((unsigned int)h) << 16);
}

// ---------------- src/dst disambiguation probe (proven) ----------------
__global__ __launch_bounds__(256)
void probe_idx(const int* __restrict__ cand, int* __restrict__ flag)
{
    const int e = blockIdx.x * 256 + threadIdx.x;
    if (e >= E_NUM) return;
    int v = cand[e];
    if (v < 0 || v >= N_OTH) atomicOr(flag, 1);
}

// ---------------- weight pack (proven) ----------------
// order: 0=Wn0, 1..4=We4..7, 5=Wn1,6=We0, 7=Wn2,8=We1, 9=Wn3,10=We2, 11=Wn4,12=We3
__global__ __launch_bounds__(256)
void pack_w(const float* __restrict__ We, const float* __restrict__ Wn,
            unsigned short* __restrict__ Wb)
{
    const int id = blockIdx.x * 256 + threadIdx.x;
    if (id >= 13 * 32768) return;
    const int wp = id >> 15;
    const int n  = (id >> 8) & 127;
    const int k  = id & 255;
    const float* S;
    if (wp == 0)      S = Wn;
    else if (wp <= 4) S = We + (size_t)(3 + wp) * 32768;
    else if (wp & 1)  S = Wn + (size_t)((wp - 3) >> 1) * 32768;
    else              S = We + (size_t)((wp - 6) >> 1) * 32768;
    Wb[id] = f2b(S[k * D_OUT + n]);
}

// ---------------- fused MFMA projection (r5/r9-proven) ----------------
// w==0 -> f32 ht (+bias) into outF (ld 256); w>0 -> bf16 table (w-1), ld 128
__global__ __launch_bounds__(256)
void proj_mfma(const float* __restrict__ X, const unsigned short* __restrict__ Wb,
               const float* __restrict__ bias, float* __restrict__ outF,
               unsigned short* __restrict__ tabs, int NW, int N)
{
    __shared__ unsigned short xs[64 * LDW];
    const int tid  = threadIdx.x;
    const int wave = tid >> 6, lane = tid & 63;
    const int r0   = blockIdx.x * 64;

    #pragma unroll
    for (int c = 0; c < 16; ++c) {
        int f = c * 256 + tid;
        int row = f >> 6, col4 = f & 63;
        int gr = r0 + row; if (gr >= N) gr = N - 1;
        float4 v = *(const float4*)(X + (size_t)gr * K_DIM + col4 * 4);
        unsigned short* p = xs + row * LDW + col4 * 4;
        p[0] = f2b(v.x); p[1] = f2b(v.y); p[2] = f2b(v.z); p[3] = f2b(v.w);
    }
    __syncthreads();

    const int n0   = wave * 32;
    const int arow = lane & 15, akd = (lane >> 4) * 8;
    const int bcol = lane & 15, bkd = (lane >> 4) * 8;
    const int rsub = (lane >> 4) * 4;

    float bias0 = 0.f, bias1 = 0.f;
    if (bias) { bias0 = bias[n0 + bcol]; bias1 = bias[n0 + 16 + bcol]; }

    for (int w = 0; w < NW; ++w) {
        f32x4 acc[4][2];
        #pragma unroll
        for (int m = 0; m < 4; ++m) {
            acc[m][0] = (f32x4){0.f, 0.f, 0.f, 0.f};
            acc[m][1] = (f32x4){0.f, 0.f, 0.f, 0.f};
        }
        const unsigned short* wb = Wb + (size_t)w * 128 * 256;
        #pragma unroll
        for (int k = 0; k < 8; ++k) {
            bf16x8 b0 = *(const bf16x8*)(wb + (size_t)(n0 + bcol) * 256 + k * 32 + bkd);
            bf16x8 b1 = *(const bf16x8*)(wb + (size_t)(n0 + 16 + bcol) * 256 + k * 32 + bkd);
            #pragma unroll
            for (int m = 0; m < 4; ++m) {
                bf16x8 a = *(const bf16x8*)(xs + (m * 16 + arow) * LDW + k * 32 + akd);
                acc[m][0] = __builtin_amdgcn_mfma_f32_16x16x32_bf16(a, b0, acc[m][0], 0, 0, 0);
                acc[m][1] = __builtin_amdgcn_mfma_f32_16x16x32_bf16(a, b1, acc[m][1], 0, 0, 0);
            }
        }
        if (w == 0) {
            #pragma unroll
            for (int m = 0; m < 4; ++m)
                #pragma unroll
                for (int nn = 0; nn < 2; ++nn) {
                    const int col = n0 + nn * 16 + bcol;
                    const float bb = nn ? bias1 : bias0;
                    #pragma unroll
                    for (int j = 0; j < 4; ++j) {
                        const int row = r0 + m * 16 + rsub + j;
                        if (row < N) outF[(size_t)row * 256 + col] = acc[m][nn][j] + bb;
                    }
                }
        } else {
            unsigned short* tw = tabs + (size_t)(w - 1) * N * D_OUT;
            #pragma unroll
            for (int m = 0; m < 4; ++m)
                #pragma unroll
                for (int nn = 0; nn < 2; ++nn) {
                    const int col = n0 + nn * 16 + bcol;
                    #pragma unroll
                    for (int j = 0; j < 4; ++j) {
                        const int row = r0 + m * 16 + rsub + j;
                        if (row < N) tw[(size_t)row * D_OUT + col] = f2b(acc[m][nn][j]);
                    }
                }
        }
    }
}

// ---------------- reciprocal row L2 norms (r9-proven) ----------------
__global__ __launch_bounds__(256)
void rownorm_f(const float* __restrict__ T, float* __restrict__ rn, int N)
{
    const int lr = threadIdx.x >> 6;
    const int l  = threadIdx.x & 63;
    const int r  = blockIdx.x * 4 + lr;
    if (r >= N) return;
    float a = T[(size_t)r * 256 + l];
    float b = T[(size_t)r * 256 + 64 + l];
    float s = a * a + b * b;
    #pragma unroll
    for (int m = 32; m; m >>= 1) s += __shfl_xor(s, m);
    if (l == 0) rn[r] = 1.f / fmaxf(sqrtf(s), EPS);
}

__global__ __launch_bounds__(256)
void rownorm_b(const unsigned short* __restrict__ T, float* __restrict__ rn, int N)
{
    const int lr = threadIdx.x >> 6;
    const int l  = threadIdx.x & 63;
    const int r  = blockIdx.x * 4 + lr;
    if (r >= N) return;
    float a = b2f(T[(size_t)r * D_OUT + l]);
    float b = b2f(T[(size_t)r * D_OUT + 64 + l]);
    float s = a * a + b * b;
    #pragma unroll
    for (int m = 32; m; m >>= 1) s += __shfl_xor(s, m);
    if (l == 0) rn[r] = 1.f / fmaxf(sqrtf(s), EPS);
}

// ---------------- edge -> (coarse bucket, packed entry) (proven) ----------------
__device__ __forceinline__ void edge_cd(const int* __restrict__ srcp,
                                        const int* __restrict__ dstp,
                                        int id, int* c_out, unsigned* entry_out)
{
    const int et = id / E_NUM;
    const int e  = id - et * E_NUM;
    int d = dstp[(size_t)et * E_NUM + e];
    if (et < 4) {
        d = d < 0 ? 0 : (d >= N_VUL ? N_VUL - 1 : d);
        *c_out = d >> 8;
        if (entry_out) {
            int s = srcp[(size_t)et * E_NUM + e];
            s = s < 0 ? 0 : (s >= N_OTH ? N_OTH - 1 : s);
            *entry_out = ((unsigned)(((d & 255) << 2) | et) << 17) | (unsigned)s;
        }
    } else {
        d = d < 0 ? 0 : (d >= N_OTH ? N_OTH - 1 : d);
        *c_out = NCV + (et - 4) * NCO_J + (d >> 8);
        if (entry_out) {
            int s = srcp[(size_t)et * E_NUM + e];
            s = s < 0 ? 0 : (s >= N_VUL ? N_VUL - 1 : s);
            *entry_out = ((unsigned)(d & 255) << 17) | (unsigned)s;
        }
    }
}

// ---------------- coarse histogram (proven) ----------------
__global__ __launch_bounds__(256)
void chist(const int* __restrict__ pA, const int* __restrict__ pB,
           const int* __restrict__ flag, int* __restrict__ ccnt)
{
    __shared__ int h[NC];
    for (int i = threadIdx.x; i < NC; i += 256) h[i] = 0;
    __syncthreads();
    const int flagv = *flag;
    const int* srcp = flagv ? pB : pA;
    const int* dstp = flagv ? pA : pB;
    const int base = blockIdx.x * 16384;
    for (int t = 0; t < 64; ++t) {
        const int id = base + t * 256 + threadIdx.x;
        if (id < TOT_E) {
            int c; edge_cd(srcp, dstp, id, &c, nullptr);
            atomicAdd(&h[c], 1);
        }
    }
    __syncthreads();
    for (int i = threadIdx.x; i < NC; i += 256)
        if (h[i]) atomicAdd(&ccnt[i], h[i]);
}

// ---------------- exclusive scan of coarse counts; writes offs[KEYS] ----------------
__global__ __launch_bounds__(256)
void cscan(const int* __restrict__ ccnt, int* __restrict__ cbase,
           int* __restrict__ ccur, int* __restrict__ offs)
{
    __shared__ int sh[256];
    __shared__ int carry;
    if (threadIdx.x == 0) carry = 0;
    __syncthreads();
    for (int b = 0; b < NC; b += 256) {
        const int i = b + threadIdx.x;
        const int v = (i < NC) ? ccnt[i] : 0;
        sh[threadIdx.x] = v;
        __syncthreads();
        for (int st = 1; st < 256; st <<= 1) {
            int t = (threadIdx.x >= st) ? sh[threadIdx.x - st] : 0;
            __syncthreads();
            sh[threadIdx.x] += t;
            __syncthreads();
        }
        const int excl = carry + sh[threadIdx.x] - v;
        if (i < NC) { cbase[i] = excl; ccur[i] = excl; }
        __syncthreads();
        if (threadIdx.x == 255) carry += sh[255];
        __syncthreads();
    }
    if (threadIdx.x == 0) offs[KEYS] = carry;   // == TOT_E
}

// ---------------- staged scatter (proven) ----------------
__global__ __launch_bounds__(256)
void cstage(const int* __restrict__ pA, const int* __restrict__ pB,
            const int* __restrict__ flag, int* __restrict__ ccur,
            unsigned* __restrict__ staging)
{
    __shared__ unsigned outE[CHUNK];
    __shared__ unsigned short binof[CHUNK];
    __shared__ int foff[NC];
    __shared__ int fcur[NC];
    __shared__ int gb[NC];
    __shared__ int sh[256];
    __shared__ int carry;

    const int flagv = *flag;
    const int* srcp = flagv ? pB : pA;
    const int* dstp = flagv ? pA : pB;
    const int base = blockIdx.x * CHUNK;
    const int n = (base + CHUNK <= TOT_E) ? CHUNK : (TOT_E - base);

    for (int i = threadIdx.x; i < NC; i += 256) foff[i] = 0;
    if (threadIdx.x == 0) carry = 0;
    __syncthreads();

    for (int t = 0; t < CHUNK / 256; ++t) {
        const int k = t * 256 + threadIdx.x;
        if (k < n) {
            int c; edge_cd(srcp, dstp, base + k, &c, nullptr);
            atomicAdd(&foff[c], 1);
        }
    }
    __syncthreads();

    for (int b = 0; b < NC; b += 256) {
        const int i = b + threadIdx.x;
        const int v = (i < NC) ? foff[i] : 0;
        sh[threadIdx.x] = v;
        __syncthreads();
        for (int st = 1; st < 256; st <<= 1) {
            int t = (threadIdx.x >= st) ? sh[threadIdx.x - st] : 0;
            __syncthreads();
            sh[threadIdx.x] += t;
            __syncthreads();
        }
        const int excl = carry + sh[threadIdx.x] - v;
        if (i < NC) {
            foff[i] = excl;
            fcur[i] = excl;
            gb[i] = v ? atomicAdd(&ccur[i], v) : 0;
        }
        __syncthreads();
        if (threadIdx.x == 255) carry += sh[255];
        __syncthreads();
    }

    for (int t = 0; t < CHUNK / 256; ++t) {
        const int k = t * 256 + threadIdx.x;
        if (k < n) {
            int c; unsigned ent;
            edge_cd(srcp, dstp, base + k, &c, &ent);
            const int p = atomicAdd(&fcur[c], 1);
            outE[p] = ent;
            binof[p] = (unsigned short)c;
        }
    }
    __syncthreads();

    for (int i = threadIdx.x; i < n; i += 256) {
        const int c = binof[i];
        staging[gb[c] + (i - foff[c])] = outE[i];
    }
}

// ---------------- fine sort (vul buckets) (proven) ----------------
__global__ __launch_bounds__(256)
void fine_sort_vul(const unsigned* __restrict__ staging,
                   const int* __restrict__ cbase, const int* __restrict__ ccnt,
                   int* __restrict__ srcs, int* __restrict__ offs)
{
    __shared__ unsigned raw[VCAP];
    __shared__ int srt[VCAP];
    __shared__ int foff[1025];
    __shared__ int fcur[1024];
    __shared__ int sh[256];
    __shared__ int carry;

    const int c = blockIdx.x;
    const int nb = min(ccnt[c], VCAP);
    const int gb = cbase[c];
    const int tid = threadIdx.x;

    for (int i = tid; i < 1024; i += 256) fcur[i] = 0;
    if (tid == 0) carry = 0;
    __syncthreads();
    for (int i = tid; i < nb; i += 256) {
        unsigned e = staging[gb + i];
        raw[i] = e;
        atomicAdd(&fcur[e >> 17], 1);
    }
    __syncthreads();
    for (int b = 0; b < 1024; b += 256) {
        const int i = b + tid;
        const int v = fcur[i];
        sh[tid] = v;
        __syncthreads();
        for (int st = 1; st < 256; st <<= 1) {
            int t = (tid >= st) ? sh[tid - st] : 0;
            __syncthreads();
            sh[tid] += t;
            __syncthreads();
        }
        foff[i] = carry + sh[tid] - v;
        __syncthreads();
        if (tid == 255) carry += sh[255];
        __syncthreads();
    }
    __syncthreads();
    for (int i = tid; i < 1024; i += 256) fcur[i] = foff[i];
    __syncthreads();
    for (int i = tid; i < nb; i += 256) {
        unsigned e = raw[i];
        const int p = atomicAdd(&fcur[e >> 17], 1);
        srt[p] = (int)(e & 0x1FFFFu);
    }
    __syncthreads();
    for (int i = tid; i < nb; i += 256) srcs[gb + i] = srt[i];
    for (int lk = tid; lk < 1024; lk += 256) {
        const int d = c * 256 + (lk >> 2);
        if (d < N_VUL) offs[c * 1024 + lk] = gb + foff[lk];
    }
}

// ---------------- fine sort (oth buckets) (proven) ----------------
__global__ __launch_bounds__(256)
void fine_sort_oth(const unsigned* __restrict__ staging,
                   const int* __restrict__ cbase, const int* __restrict__ ccnt,
                   int* __restrict__ srcs, int* __restrict__ offs)
{
    __shared__ unsigned raw[OCAP];
    __shared__ int srt[OCAP];
    __shared__ int foff[257];
    __shared__ int fcur[256];
    __shared__ int sh[256];

    const int co = blockIdx.x;
    const int j = co / NCO_J, dg = co - j * NCO_J;
    const int c = NCV + co;
    const int nb = min(ccnt[c], OCAP);
    const int gb = cbase[c];
    const int tid = threadIdx.x;

    fcur[tid] = 0;
    __syncthreads();
    for (int i = tid; i < nb; i += 256) {
        unsigned e = staging[gb + i];
        raw[i] = e;
        atomicAdd(&fcur[e >> 17], 1);
    }
    __syncthreads();
    {
        const int v = fcur[tid];
        sh[tid] = v;
        __syncthreads();
        for (int st = 1; st < 256; st <<= 1) {
            int t = (tid >= st) ? sh[tid - st] : 0;
            __syncthreads();
            sh[tid] += t;
            __syncthreads();
        }
        foff[tid] = sh[tid] - v;
        if (tid == 255) foff[256] = sh[255];
        __syncthreads();
        fcur[tid] = foff[tid];
    }
    __syncthreads();
    for (int i = tid; i < nb; i += 256) {
        unsigned e = raw[i];
        const int p = atomicAdd(&fcur[e >> 17], 1);
        srt[p] = (int)(e & 0x1FFFFu);
    }
    __syncthreads();
    for (int i = tid; i < nb; i += 256) srcs[gb + i] = srt[i];
    {
        const int d = dg * 256 + tid;
        if (d < N_OTH) offs[VKEYS + j * N_OTH + d] = gb + foff[tid];
    }
}

// ---------------- vul aggregation: 2 waves per dst (halved dependent chain) ----------------
// block = 256 thr = 4 waves = 2 dsts; wave (dstL, half) handles etypes {2*half, 2*half+1}
__global__ __launch_bounds__(256)
void vul_gather(const int* __restrict__ srcs, const int* __restrict__ offs,
                const unsigned short* __restrict__ othTab,
                const float* __restrict__ rinHrS,
                const float* __restrict__ rinHtVul,
                float* __restrict__ out)
{
    __shared__ float ssh[2][4];
    __shared__ float part[2][2][128];

    const int wv = threadIdx.x >> 6;
    const int dstL = wv >> 1, half = wv & 1;
    const int d = blockIdx.x * 2 + dstL;
    const int lane = threadIdx.x & 63;
    const int g = lane >> 4, l = lane & 15;

    const float* hrow = out + (size_t)d * 256 + l * 8;
    float b0[8];
    {
        float4 t0 = *(const float4*)(hrow);
        float4 t1 = *(const float4*)(hrow + 4);
        b0[0] = t0.x; b0[1] = t0.y; b0[2] = t0.z; b0[3] = t0.w;
        b0[4] = t1.x; b0[5] = t1.y; b0[6] = t1.z; b0[7] = t1.w;
    }
    const float rnb = rinHtVul[d];

    float acc[2][8];
    float ss[2];
    #pragma unroll
    for (int e = 0; e < 2; ++e) {
        ss[e] = 0.f;
        #pragma unroll
        for (int j = 0; j < 8; ++j) acc[e][j] = 0.f;
    }

    #pragma unroll
    for (int etl = 0; etl < 2; ++etl) {
        const int et = half * 2 + etl;
        const unsigned short* T = othTab + (size_t)et * NO128;
        const float* rA = rinHrS + (size_t)et * N_OTH;
        const int k0 = offs[d * 4 + et], k1 = offs[d * 4 + et + 1];
        for (int p0 = k0; p0 < k1; p0 += 4) {
            const int p = p0 + g;
            const bool ok = (p < k1);
            const int s = srcs[ok ? p : k0];
            bf16x8 av = *(const bf16x8*)(T + (size_t)s * 128 + l * 8);
            float a[8];
            #pragma unroll
            for (int j = 0; j < 8; ++j) a[j] = b2f((unsigned short)av[j]);
            float dp = 0.f;
            #pragma unroll
            for (int j = 0; j < 8; ++j) dp = fmaf(a[j], b0[j], dp);
            dp += __shfl_xor(dp, 1); dp += __shfl_xor(dp, 2);
            dp += __shfl_xor(dp, 4); dp += __shfl_xor(dp, 8);
            const float v = ok ? dp * rA[s] * rnb : 0.f;
            ss[etl] += v;
            #pragma unroll
            for (int j = 0; j < 8; ++j) acc[etl][j] = fmaf(v, a[j], acc[etl][j]);
        }
    }

    // full-wave score sums (merge the 4 groups)
    #pragma unroll
    for (int e = 0; e < 2; ++e) {
        float t = ss[e];
        t += __shfl_xor(t, 16); t += __shfl_xor(t, 32);
        ss[e] = t;
    }
    if (lane == 0) { ssh[dstL][half * 2] = ss[0]; ssh[dstL][half * 2 + 1] = ss[1]; }
    __syncthreads();

    const int o0 = offs[d * 4], o1 = offs[d * 4 + 1], o2 = offs[d * 4 + 2],
              o3 = offs[d * 4 + 3], o4 = offs[d * 4 + 4];
    const float m0 = ssh[dstL][0] / fmaxf((float)(o1 - o0), 1.f);
    const float m1 = ssh[dstL][1] / fmaxf((float)(o2 - o1), 1.f);
    const float m2 = ssh[dstL][2] / fmaxf((float)(o3 - o2), 1.f);
    const float m3 = ssh[dstL][3] / fmaxf((float)(o4 - o3), 1.f);
    const float e0 = expf(m0), e1 = expf(m1), e2 = expf(m2), e3 = expf(m3);
    const float wp = 0.6f / (e0 + e1), wn = 0.4f / (e2 + e3);
    const float wA = half ? e2 * wn : e0 * wp;
    const float wB = half ? e3 * wn : e1 * wp;

    float res[8];
    #pragma unroll
    for (int j = 0; j < 8; ++j) {
        float t = wA * acc[0][j] + wB * acc[1][j];
        t += __shfl_xor(t, 16); t += __shfl_xor(t, 32);
        res[j] = t;
    }
    if (g == 0) {
        #pragma unroll
        for (int j = 0; j < 8; ++j) part[dstL][half][l * 8 + j] = res[j];
    }
    __syncthreads();

    {
        const int dd = threadIdx.x >> 7, c = threadIdx.x & 127;
        const int dg2 = blockIdx.x * 2 + dd;
        out[(size_t)dg2 * 256 + 128 + c] = part[dd][0][c] + part[dd][1][c];
    }
}

// ---------------- oth aggregation (r9-proven, contiguous vulTab) ----------------
__global__ __launch_bounds__(256)
void oth_gather(const int* __restrict__ srcs, const int* __restrict__ offs,
                const unsigned short* __restrict__ vulTab,
                const float* __restrict__ rinHrB,
                const float* __restrict__ rinHtOth,
                float* __restrict__ outO)
{
    const int j = threadIdx.x >> 6;
    const int d = blockIdx.x;
    const int lane = threadIdx.x & 63;
    const int g = lane >> 4, l = lane & 15;

    const float* hrow = outO + ((size_t)j * N_OTH + d) * 256 + l * 8;
    float b0[8];
    {
        float4 t0 = *(const float4*)(hrow);
        float4 t1 = *(const float4*)(hrow + 4);
        b0[0] = t0.x; b0[1] = t0.y; b0[2] = t0.z; b0[3] = t0.w;
        b0[4] = t1.x; b0[5] = t1.y; b0[6] = t1.z; b0[7] = t1.w;
    }
    const float rnb = rinHtOth[j * N_OTH + d];
    const unsigned short* A = vulTab + (size_t)j * NV128;
    const unsigned short* M = vulTab + (size_t)3 * NV128;   // hr_final[0] = We[7] proj
    const float* rA = rinHrB + (size_t)j * N_VUL;

    const int key = VKEYS + j * N_OTH + d;
    const int k0 = offs[key], k1 = offs[key + 1];

    float acc[8];
    #pragma unroll
    for (int jj = 0; jj < 8; ++jj) acc[jj] = 0.f;

    for (int p0 = k0; p0 < k1; p0 += 4) {
        const int p = p0 + g;
        const bool ok = (p < k1);
        const int s = srcs[ok ? p : k0];
        bf16x8 av = *(const bf16x8*)(A + (size_t)s * 128 + l * 8);
        float a[8];
        #pragma unroll
        for (int jj = 0; jj < 8; ++jj) a[jj] = b2f((unsigned short)av[jj]);
        float dp = 0.f;
        #pragma unroll
        for (int jj = 0; jj < 8; ++jj) dp = fmaf(a[jj], b0[jj], dp);
        dp += __shfl_xor(dp, 1); dp += __shfl_xor(dp, 2);
        dp += __shfl_xor(dp, 4); dp += __shfl_xor(dp, 8);
        const float v = ok ? dp * rA[s] * rnb : 0.f;
        if (j == 3) {
            #pragma unroll
            for (int jj = 0; jj < 8; ++jj) acc[jj] = fmaf(v, a[jj], acc[jj]);
        } else {
            bf16x8 mv = *(const bf16x8*)(M + (size_t)s * 128 + l * 8);
            #pragma unroll
            for (int jj = 0; jj < 8; ++jj) acc[jj] = fmaf(v, b2f((unsigned short)mv[jj]), acc[jj]);
        }
    }

    #pragma unroll
    for (int jj = 0; jj < 8; ++jj) {
        float t = acc[jj];
        t += __shfl_xor(t, 16); t += __shfl_xor(t, 32);
        acc[jj] = t;
    }
    if (g == 0) {
        float4 r0 = {acc[0], acc[1], acc[2], acc[3]};
        float4 r1 = {acc[4], acc[5], acc[6], acc[7]};
        float* o = outO + ((size_t)j * N_OTH + d) * 256 + 128 + l * 8;
        *(float4*)(o) = r0;
        *(float4*)(o + 4) = r1;
    }
}

extern "C" void kernel_launch(void* const* d_in, const int* in_sizes, int n_in,
                              void* d_out, int out_size, void* d_ws, size_t ws_size,
                              hipStream_t stream)
{
    // ---- size-based input resolution (proven) ----
    int i_fv = 0, i_fo = 1, i_We = 2, i_Wn = 3, i_bn = 4, i_iA = 5, i_iB = 6;
    {
        int a = -1, b = -1;
        for (int i = 0; i < n_in; ++i) {
            switch (in_sizes[i]) {
                case 25600000: i_fv = i; break;
                case 20480000: i_fo = i; break;
                case   262144: i_We = i; break;
                case   163840: i_Wn = i; break;
                case      640: i_bn = i; break;
                case  3200000: if (a < 0) a = i; else b = i; break;
                default: break;
            }
        }
        if (a >= 0 && b >= 0) { i_iA = a; i_iB = b; }
    }
    const float* feat_vul = (const float*)d_in[i_fv];
    const float* feat_oth = (const float*)d_in[i_fo];
    const float* We = (const float*)d_in[i_We];
    const float* Wn = (const float*)d_in[i_Wn];
    const float* bn = (const float*)d_in[i_bn];
    const int* idxA = (const int*)d_in[i_iA];
    const int* idxB = (const int*)d_in[i_iB];
    float* out = (float*)d_out;

    // ---- workspace carve (~150 MB) ----
    int*      flag    = (int*)d_ws;                       // 4 (zeroed)
    int*      ccnt    = flag + 4;                         // NC (zeroed)
    int*      cbase   = ccnt + NC;                        // NC
    int*      ccur    = cbase + NC;                       // NC
    unsigned* staging = (unsigned*)(ccur + NC);           // TOT_E
    int*      srcs    = (int*)(staging + TOT_E);          // TOT_E
    int*      offs    = srcs + TOT_E;                     // KEYS+1
    float*    rinHtVul = (float*)(offs + KEYS + 1);       // N_VUL
    float*    rinHtOth = rinHtVul + N_VUL;                // 4*N_OTH
    float*    rinHrB   = rinHtOth + (size_t)4 * N_OTH;    // 4*N_VUL
    float*    rinHrS   = rinHrB + (size_t)4 * N_VUL;      // 4*N_OTH
    unsigned short* vulTab = (unsigned short*)(rinHrS + (size_t)4 * N_OTH); // 4*NV128
    unsigned short* othTab = vulTab + 4 * NV128;          // 4*NO128
    unsigned short* Wb     = othTab + 4 * NO128;          // 13*32768

    hipMemsetAsync(d_ws, 0, (4 + (size_t)NC) * sizeof(int), stream);

    probe_idx<<<(E_NUM + 255) / 256, 256, 0, stream>>>(idxA, flag);
    pack_w<<<(13 * 32768 + 255) / 256, 256, 0, stream>>>(We, Wn, Wb);

    const size_t OUT0 = (size_t)N_VUL * 256;

    // projections: vul -> ht(f32)+hrB0..3(bf16); oth i -> ht_i(f32)+hrS_i(bf16)
    proj_mfma<<<(N_VUL + 63) / 64, 256, 0, stream>>>(
        feat_vul, Wb, bn, out, vulTab, 5, N_VUL);
    for (int i = 0; i < 4; ++i)
        proj_mfma<<<(N_OTH + 63) / 64, 256, 0, stream>>>(
            feat_oth + (size_t)i * N_OTH * K_DIM,
            Wb + (size_t)(5 + 2 * i) * 32768,
            bn + (size_t)(i + 1) * D_OUT,
            out + OUT0 + (size_t)i * N_OTH * 256,
            othTab + (size_t)i * NO128, 2, N_OTH);

    // reciprocal norms
    rownorm_f<<<(N_VUL + 3) / 4, 256, 0, stream>>>(out, rinHtVul, N_VUL);
    rownorm_f<<<(4 * N_OTH + 3) / 4, 256, 0, stream>>>(out + OUT0, rinHtOth, 4 * N_OTH);
    rownorm_b<<<(4 * N_VUL + 3) / 4, 256, 0, stream>>>(vulTab, rinHrB, 4 * N_VUL);
    rownorm_b<<<(4 * N_OTH + 3) / 4, 256, 0, stream>>>(othTab, rinHrS, 4 * N_OTH);

    // coarse-bucketed coalesced staging, then per-bucket LDS fine sort -> global CSR
    chist<<<(TOT_E + 16383) / 16384, 256, 0, stream>>>(idxA, idxB, flag, ccnt);
    cscan<<<1, 256, 0, stream>>>(ccnt, cbase, ccur, offs);
    cstage<<<(TOT_E + CHUNK - 1) / CHUNK, 256, 0, stream>>>(idxA, idxB, flag, ccur, staging);
    fine_sort_vul<<<NCV, 256, 0, stream>>>(staging, cbase, ccnt, srcs, offs);
    fine_sort_oth<<<4 * NCO_J, 256, 0, stream>>>(staging, cbase, ccnt, srcs, offs);

    // gathers: vul = 2 waves/dst (new), oth = r9-proven
    vul_gather<<<N_VUL / 2, 256, 0, stream>>>(srcs, offs, othTab, rinHrS, rinHtVul, out);
    oth_gather<<<N_OTH, 256, 0, stream>>>(srcs, offs, vulTab, rinHrB, rinHtOth, out + OUT0);
}

// Round 13
// 709.299 us; speedup vs baseline: 1.3401x; 1.1130x over previous
//
#include <hip/hip_runtime.h>

#define N_VUL 100000
#define N_OTH 20000
#define E_NUM 400000
#define K_DIM 256
#define D_OUT 128
#define EPS 1e-8f
#define LDW 264   // padded LDS row (bf16 elems)

#define NCV 391               // ceil(N_VUL/256) coarse buckets (vul side)
#define NCO_J 79              // ceil(N_OTH/256) per etype j (oth side)
#define NC (NCV + 4 * NCO_J)  // 707 total coarse buckets
#define TOT_E (8 * E_NUM)     // 3,200,000 edges
#define CHUNK 8192            // edges per cstage block
#define VCAP 5120             // max edges per vul bucket
#define OCAP 6144             // max edges per oth bucket
#define VKEYS (4 * N_VUL)
#define KEYS  (4 * N_VUL + 4 * N_OTH)

typedef __attribute__((ext_vector_type(8))) short bf16x8;
typedef __attribute__((ext_vector_type(4))) float f32x4;

static const size_t NV128 = (size_t)N_VUL * 128;
static const size_t NO128 = (size_t)N_OTH * 128;

__device__ __forceinline__ unsigned short f2b(float f) {
    unsigned int u = __float_as_uint(f);
    u += 0x7FFFu + ((u >> 16) & 1u);
    return (unsigned short)(u >> 16);
}
__device__ __forceinline__ float b2f(unsigned short h) {
    return __uint_as_float(((unsigned int)h) << 16);
}

// ---------------- src/dst disambiguation probe (proven) ----------------
__global__ __launch_bounds__(256)
void probe_idx(const int* __restrict__ cand, int* __restrict__ flag)
{
    const int e = blockIdx.x * 256 + threadIdx.x;
    if (e >= E_NUM) return;
    int v = cand[e];
    if (v < 0 || v >= N_OTH) atomicOr(flag, 1);
}

// ---------------- weight pack (proven) ----------------
// order: 0=Wn0, 1..4=We4..7, 5=Wn1,6=We0, 7=Wn2,8=We1, 9=Wn3,10=We2, 11=Wn4,12=We3
__global__ __launch_bounds__(256)
void pack_w(const float* __restrict__ We, const float* __restrict__ Wn,
            unsigned short* __restrict__ Wb)
{
    const int id = blockIdx.x * 256 + threadIdx.x;
    if (id >= 13 * 32768) return;
    const int wp = id >> 15;
    const int n  = (id >> 8) & 127;
    const int k  = id & 255;
    const float* S;
    if (wp == 0)      S = Wn;
    else if (wp <= 4) S = We + (size_t)(3 + wp) * 32768;
    else if (wp & 1)  S = Wn + (size_t)((wp - 3) >> 1) * 32768;
    else              S = We + (size_t)((wp - 6) >> 1) * 32768;
    Wb[id] = f2b(S[k * D_OUT + n]);
}

// ---------------- fused MFMA projection (r5/r9-proven) ----------------
// w==0 -> f32 ht (+bias) into outF (ld 256); w>0 -> bf16 table (w-1), ld 128
__global__ __launch_bounds__(256)
void proj_mfma(const float* __restrict__ X, const unsigned short* __restrict__ Wb,
               const float* __restrict__ bias, float* __restrict__ outF,
               unsigned short* __restrict__ tabs, int NW, int N)
{
    __shared__ unsigned short xs[64 * LDW];
    const int tid  = threadIdx.x;
    const int wave = tid >> 6, lane = tid & 63;
    const int r0   = blockIdx.x * 64;

    #pragma unroll
    for (int c = 0; c < 16; ++c) {
        int f = c * 256 + tid;
        int row = f >> 6, col4 = f & 63;
        int gr = r0 + row; if (gr >= N) gr = N - 1;
        float4 v = *(const float4*)(X + (size_t)gr * K_DIM + col4 * 4);
        unsigned short* p = xs + row * LDW + col4 * 4;
        p[0] = f2b(v.x); p[1] = f2b(v.y); p[2] = f2b(v.z); p[3] = f2b(v.w);
    }
    __syncthreads();

    const int n0   = wave * 32;
    const int arow = lane & 15, akd = (lane >> 4) * 8;
    const int bcol = lane & 15, bkd = (lane >> 4) * 8;
    const int rsub = (lane >> 4) * 4;

    float bias0 = 0.f, bias1 = 0.f;
    if (bias) { bias0 = bias[n0 + bcol]; bias1 = bias[n0 + 16 + bcol]; }

    for (int w = 0; w < NW; ++w) {
        f32x4 acc[4][2];
        #pragma unroll
        for (int m = 0; m < 4; ++m) {
            acc[m][0] = (f32x4){0.f, 0.f, 0.f, 0.f};
            acc[m][1] = (f32x4){0.f, 0.f, 0.f, 0.f};
        }
        const unsigned short* wb = Wb + (size_t)w * 128 * 256;
        #pragma unroll
        for (int k = 0; k < 8; ++k) {
            bf16x8 b0 = *(const bf16x8*)(wb + (size_t)(n0 + bcol) * 256 + k * 32 + bkd);
            bf16x8 b1 = *(const bf16x8*)(wb + (size_t)(n0 + 16 + bcol) * 256 + k * 32 + bkd);
            #pragma unroll
            for (int m = 0; m < 4; ++m) {
                bf16x8 a = *(const bf16x8*)(xs + (m * 16 + arow) * LDW + k * 32 + akd);
                acc[m][0] = __builtin_amdgcn_mfma_f32_16x16x32_bf16(a, b0, acc[m][0], 0, 0, 0);
                acc[m][1] = __builtin_amdgcn_mfma_f32_16x16x32_bf16(a, b1, acc[m][1], 0, 0, 0);
            }
        }
        if (w == 0) {
            #pragma unroll
            for (int m = 0; m < 4; ++m)
                #pragma unroll
                for (int nn = 0; nn < 2; ++nn) {
                    const int col = n0 + nn * 16 + bcol;
                    const float bb = nn ? bias1 : bias0;
                    #pragma unroll
                    for (int j = 0; j < 4; ++j) {
                        const int row = r0 + m * 16 + rsub + j;
                        if (row < N) outF[(size_t)row * 256 + col] = acc[m][nn][j] + bb;
                    }
                }
        } else {
            unsigned short* tw = tabs + (size_t)(w - 1) * N * D_OUT;
            #pragma unroll
            for (int m = 0; m < 4; ++m)
                #pragma unroll
                for (int nn = 0; nn < 2; ++nn) {
                    const int col = n0 + nn * 16 + bcol;
                    #pragma unroll
                    for (int j = 0; j < 4; ++j) {
                        const int row = r0 + m * 16 + rsub + j;
                        if (row < N) tw[(size_t)row * D_OUT + col] = f2b(acc[m][nn][j]);
                    }
                }
        }
    }
}

// ---------------- reciprocal row L2 norms (r9-proven) ----------------
__global__ __launch_bounds__(256)
void rownorm_f(const float* __restrict__ T, float* __restrict__ rn, int N)
{
    const int lr = threadIdx.x >> 6;
    const int l  = threadIdx.x & 63;
    const int r  = blockIdx.x * 4 + lr;
    if (r >= N) return;
    float a = T[(size_t)r * 256 + l];
    float b = T[(size_t)r * 256 + 64 + l];
    float s = a * a + b * b;
    #pragma unroll
    for (int m = 32; m; m >>= 1) s += __shfl_xor(s, m);
    if (l == 0) rn[r] = 1.f / fmaxf(sqrtf(s), EPS);
}

__global__ __launch_bounds__(256)
void rownorm_b(const unsigned short* __restrict__ T, float* __restrict__ rn, int N)
{
    const int lr = threadIdx.x >> 6;
    const int l  = threadIdx.x & 63;
    const int r  = blockIdx.x * 4 + lr;
    if (r >= N) return;
    float a = b2f(T[(size_t)r * D_OUT + l]);
    float b = b2f(T[(size_t)r * D_OUT + 64 + l]);
    float s = a * a + b * b;
    #pragma unroll
    for (int m = 32; m; m >>= 1) s += __shfl_xor(s, m);
    if (l == 0) rn[r] = 1.f / fmaxf(sqrtf(s), EPS);
}

// ---------------- edge -> (coarse bucket, packed entry) (proven) ----------------
__device__ __forceinline__ void edge_cd(const int* __restrict__ srcp,
                                        const int* __restrict__ dstp,
                                        int id, int* c_out, unsigned* entry_out)
{
    const int et = id / E_NUM;
    const int e  = id - et * E_NUM;
    int d = dstp[(size_t)et * E_NUM + e];
    if (et < 4) {
        d = d < 0 ? 0 : (d >= N_VUL ? N_VUL - 1 : d);
        *c_out = d >> 8;
        if (entry_out) {
            int s = srcp[(size_t)et * E_NUM + e];
            s = s < 0 ? 0 : (s >= N_OTH ? N_OTH - 1 : s);
            *entry_out = ((unsigned)(((d & 255) << 2) | et) << 17) | (unsigned)s;
        }
    } else {
        d = d < 0 ? 0 : (d >= N_OTH ? N_OTH - 1 : d);
        *c_out = NCV + (et - 4) * NCO_J + (d >> 8);
        if (entry_out) {
            int s = srcp[(size_t)et * E_NUM + e];
            s = s < 0 ? 0 : (s >= N_VUL ? N_VUL - 1 : s);
            *entry_out = ((unsigned)(d & 255) << 17) | (unsigned)s;
        }
    }
}

// ---------------- coarse histogram (proven) ----------------
__global__ __launch_bounds__(256)
void chist(const int* __restrict__ pA, const int* __restrict__ pB,
           const int* __restrict__ flag, int* __restrict__ ccnt)
{
    __shared__ int h[NC];
    for (int i = threadIdx.x; i < NC; i += 256) h[i] = 0;
    __syncthreads();
    const int flagv = *flag;
    const int* srcp = flagv ? pB : pA;
    const int* dstp = flagv ? pA : pB;
    const int base = blockIdx.x * 16384;
    for (int t = 0; t < 64; ++t) {
        const int id = base + t * 256 + threadIdx.x;
        if (id < TOT_E) {
            int c; edge_cd(srcp, dstp, id, &c, nullptr);
            atomicAdd(&h[c], 1);
        }
    }
    __syncthreads();
    for (int i = threadIdx.x; i < NC; i += 256)
        if (h[i]) atomicAdd(&ccnt[i], h[i]);
}

// ---------------- exclusive scan of coarse counts; writes offs[KEYS] ----------------
__global__ __launch_bounds__(256)
void cscan(const int* __restrict__ ccnt, int* __restrict__ cbase,
           int* __restrict__ ccur, int* __restrict__ offs)
{
    __shared__ int sh[256];
    __shared__ int carry;
    if (threadIdx.x == 0) carry = 0;
    __syncthreads();
    for (int b = 0; b < NC; b += 256) {
        const int i = b + threadIdx.x;
        const int v = (i < NC) ? ccnt[i] : 0;
        sh[threadIdx.x] = v;
        __syncthreads();
        for (int st = 1; st < 256; st <<= 1) {
            int t = (threadIdx.x >= st) ? sh[threadIdx.x - st] : 0;
            __syncthreads();
            sh[threadIdx.x] += t;
            __syncthreads();
        }
        const int excl = carry + sh[threadIdx.x] - v;
        if (i < NC) { cbase[i] = excl; ccur[i] = excl; }
        __syncthreads();
        if (threadIdx.x == 255) carry += sh[255];
        __syncthreads();
    }
    if (threadIdx.x == 0) offs[KEYS] = carry;   // == TOT_E
}

// ---------------- staged scatter (proven) ----------------
__global__ __launch_bounds__(256)
void cstage(const int* __restrict__ pA, const int* __restrict__ pB,
            const int* __restrict__ flag, int* __restrict__ ccur,
            unsigned* __restrict__ staging)
{
    __shared__ unsigned outE[CHUNK];
    __shared__ unsigned short binof[CHUNK];
    __shared__ int foff[NC];
    __shared__ int fcur[NC];
    __shared__ int gb[NC];
    __shared__ int sh[256];
    __shared__ int carry;

    const int flagv = *flag;
    const int* srcp = flagv ? pB : pA;
    const int* dstp = flagv ? pA : pB;
    const int base = blockIdx.x * CHUNK;
    const int n = (base + CHUNK <= TOT_E) ? CHUNK : (TOT_E - base);

    for (int i = threadIdx.x; i < NC; i += 256) foff[i] = 0;
    if (threadIdx.x == 0) carry = 0;
    __syncthreads();

    for (int t = 0; t < CHUNK / 256; ++t) {
        const int k = t * 256 + threadIdx.x;
        if (k < n) {
            int c; edge_cd(srcp, dstp, base + k, &c, nullptr);
            atomicAdd(&foff[c], 1);
        }
    }
    __syncthreads();

    for (int b = 0; b < NC; b += 256) {
        const int i = b + threadIdx.x;
        const int v = (i < NC) ? foff[i] : 0;
        sh[threadIdx.x] = v;
        __syncthreads();
        for (int st = 1; st < 256; st <<= 1) {
            int t = (threadIdx.x >= st) ? sh[threadIdx.x - st] : 0;
            __syncthreads();
            sh[threadIdx.x] += t;
            __syncthreads();
        }
        const int excl = carry + sh[threadIdx.x] - v;
        if (i < NC) {
            foff[i] = excl;
            fcur[i] = excl;
            gb[i] = v ? atomicAdd(&ccur[i], v) : 0;
        }
        __syncthreads();
        if (threadIdx.x == 255) carry += sh[255];
        __syncthreads();
    }

    for (int t = 0; t < CHUNK / 256; ++t) {
        const int k = t * 256 + threadIdx.x;
        if (k < n) {
            int c; unsigned ent;
            edge_cd(srcp, dstp, base + k, &c, &ent);
            const int p = atomicAdd(&fcur[c], 1);
            outE[p] = ent;
            binof[p] = (unsigned short)c;
        }
    }
    __syncthreads();

    for (int i = threadIdx.x; i < n; i += 256) {
        const int c = binof[i];
        staging[gb[c] + (i - foff[c])] = outE[i];
    }
}

// ---------------- fine sort (vul buckets) (proven) ----------------
__global__ __launch_bounds__(256)
void fine_sort_vul(const unsigned* __restrict__ staging,
                   const int* __restrict__ cbase, const int* __restrict__ ccnt,
                   int* __restrict__ srcs, int* __restrict__ offs)
{
    __shared__ unsigned raw[VCAP];
    __shared__ int srt[VCAP];
    __shared__ int foff[1025];
    __shared__ int fcur[1024];
    __shared__ int sh[256];
    __shared__ int carry;

    const int c = blockIdx.x;
    const int nb = min(ccnt[c], VCAP);
    const int gb = cbase[c];
    const int tid = threadIdx.x;

    for (int i = tid; i < 1024; i += 256) fcur[i] = 0;
    if (tid == 0) carry = 0;
    __syncthreads();
    for (int i = tid; i < nb; i += 256) {
        unsigned e = staging[gb + i];
        raw[i] = e;
        atomicAdd(&fcur[e >> 17], 1);
    }
    __syncthreads();
    for (int b = 0; b < 1024; b += 256) {
        const int i = b + tid;
        const int v = fcur[i];
        sh[tid] = v;
        __syncthreads();
        for (int st = 1; st < 256; st <<= 1) {
            int t = (tid >= st) ? sh[tid - st] : 0;
            __syncthreads();
            sh[tid] += t;
            __syncthreads();
        }
        foff[i] = carry + sh[tid] - v;
        __syncthreads();
        if (tid == 255) carry += sh[255];
        __syncthreads();
    }
    __syncthreads();
    for (int i = tid; i < 1024; i += 256) fcur[i] = foff[i];
    __syncthreads();
    for (int i = tid; i < nb; i += 256) {
        unsigned e = raw[i];
        const int p = atomicAdd(&fcur[e >> 17], 1);
        srt[p] = (int)(e & 0x1FFFFu);
    }
    __syncthreads();
    for (int i = tid; i < nb; i += 256) srcs[gb + i] = srt[i];
    for (int lk = tid; lk < 1024; lk += 256) {
        const int d = c * 256 + (lk >> 2);
        if (d < N_VUL) offs[c * 1024 + lk] = gb + foff[lk];
    }
}

// ---------------- fine sort (oth buckets) (proven) ----------------
__global__ __launch_bounds__(256)
void fine_sort_oth(const unsigned* __restrict__ staging,
                   const int* __restrict__ cbase, const int* __restrict__ ccnt,
                   int* __restrict__ srcs, int* __restrict__ offs)
{
    __shared__ unsigned raw[OCAP];
    __shared__ int srt[OCAP];
    __shared__ int foff[257];
    __shared__ int fcur[256];
    __shared__ int sh[256];

    const int co = blockIdx.x;
    const int j = co / NCO_J, dg = co - j * NCO_J;
    const int c = NCV + co;
    const int nb = min(ccnt[c], OCAP);
    const int gb = cbase[c];
    const int tid = threadIdx.x;

    fcur[tid] = 0;
    __syncthreads();
    for (int i = tid; i < nb; i += 256) {
        unsigned e = staging[gb + i];
        raw[i] = e;
        atomicAdd(&fcur[e >> 17], 1);
    }
    __syncthreads();
    {
        const int v = fcur[tid];
        sh[tid] = v;
        __syncthreads();
        for (int st = 1; st < 256; st <<= 1) {
            int t = (tid >= st) ? sh[tid - st] : 0;
            __syncthreads();
            sh[tid] += t;
            __syncthreads();
        }
        foff[tid] = sh[tid] - v;
        if (tid == 255) foff[256] = sh[255];
        __syncthreads();
        fcur[tid] = foff[tid];
    }
    __syncthreads();
    for (int i = tid; i < nb; i += 256) {
        unsigned e = raw[i];
        const int p = atomicAdd(&fcur[e >> 17], 1);
        srt[p] = (int)(e & 0x1FFFFu);
    }
    __syncthreads();
    for (int i = tid; i < nb; i += 256) srcs[gb + i] = srt[i];
    {
        const int d = dg * 256 + tid;
        if (d < N_OTH) offs[VKEYS + j * N_OTH + d] = gb + foff[tid];
    }
}

// ---------------- vul aggregation: wave per dst, first-chunk ILP hoist ----------------
// Mean segment len == 4 == one chunk, so phase-split issues all 4 etypes' loads
// together (2 dependent latencies instead of 8); tails (len>4) fall to r9 loop.
__global__ __launch_bounds__(256)
void vul_gather(const int* __restrict__ srcs, const int* __restrict__ offs,
                const unsigned short* __restrict__ othTab,
                const float* __restrict__ rinHrS,
                const float* __restrict__ rinHtVul,
                float* __restrict__ out)
{
    const int d = blockIdx.x * 4 + (threadIdx.x >> 6);
    const int lane = threadIdx.x & 63;
    const int g = lane >> 4, l = lane & 15;

    const float* hrow = out + (size_t)d * 256 + l * 8;
    float b0[8];
    {
        float4 t0 = *(const float4*)(hrow);
        float4 t1 = *(const float4*)(hrow + 4);
        b0[0] = t0.x; b0[1] = t0.y; b0[2] = t0.z; b0[3] = t0.w;
        b0[4] = t1.x; b0[5] = t1.y; b0[6] = t1.z; b0[7] = t1.w;
    }
    const float rnb = rinHtVul[d];

    int k0[4], k1[4];
    #pragma unroll
    for (int et = 0; et < 4; ++et) {
        k0[et] = offs[d * 4 + et];
        k1[et] = offs[d * 4 + et + 1];
    }

    float acc[4][8];
    float ss[4];
    #pragma unroll
    for (int et = 0; et < 4; ++et) {
        ss[et] = 0.f;
        #pragma unroll
        for (int j = 0; j < 8; ++j) acc[et][j] = 0.f;
    }

    // phase 1: first-chunk src indices for ALL etypes (4 independent loads)
    int sf[4]; bool okf[4];
    #pragma unroll
    for (int et = 0; et < 4; ++et) {
        const int p = k0[et] + g;
        okf[et] = (p < k1[et]);
        sf[et] = srcs[okf[et] ? p : k0[et]];
    }
    // phase 2: first-chunk rows + norms (8 independent loads)
    bf16x8 rowf[4];
    float rnf[4];
    #pragma unroll
    for (int et = 0; et < 4; ++et) {
        rowf[et] = *(const bf16x8*)(othTab + (size_t)et * NO128 + (size_t)sf[et] * 128 + l * 8);
        rnf[et] = rinHrS[(size_t)et * N_OTH + sf[et]];
    }
    // phase 3: compute first chunk for all etypes
    #pragma unroll
    for (int et = 0; et < 4; ++et) {
        float a[8];
        #pragma unroll
        for (int j = 0; j < 8; ++j) a[j] = b2f((unsigned short)rowf[et][j]);
        float dp = 0.f;
        #pragma unroll
        for (int j = 0; j < 8; ++j) dp = fmaf(a[j], b0[j], dp);
        dp += __shfl_xor(dp, 1); dp += __shfl_xor(dp, 2);
        dp += __shfl_xor(dp, 4); dp += __shfl_xor(dp, 8);
        const float v = okf[et] ? dp * rnf[et] * rnb : 0.f;
        ss[et] += v;
        #pragma unroll
        for (int j = 0; j < 8; ++j) acc[et][j] = fmaf(v, a[j], acc[et][j]);
    }
    // phase 4: tails (len > 4), r9 serial loop
    #pragma unroll
    for (int et = 0; et < 4; ++et) {
        const unsigned short* T = othTab + (size_t)et * NO128;
        const float* rA = rinHrS + (size_t)et * N_OTH;
        for (int p0 = k0[et] + 4; p0 < k1[et]; p0 += 4) {
            const int p = p0 + g;
            const bool ok = (p < k1[et]);
            const int s = srcs[ok ? p : k0[et]];
            bf16x8 av = *(const bf16x8*)(T + (size_t)s * 128 + l * 8);
            float a[8];
            #pragma unroll
            for (int j = 0; j < 8; ++j) a[j] = b2f((unsigned short)av[j]);
            float dp = 0.f;
            #pragma unroll
            for (int j = 0; j < 8; ++j) dp = fmaf(a[j], b0[j], dp);
            dp += __shfl_xor(dp, 1); dp += __shfl_xor(dp, 2);
            dp += __shfl_xor(dp, 4); dp += __shfl_xor(dp, 8);
            const float v = ok ? dp * rA[s] * rnb : 0.f;
            ss[et] += v;
            #pragma unroll
            for (int j = 0; j < 8; ++j) acc[et][j] = fmaf(v, a[j], acc[et][j]);
        }
    }

    #pragma unroll
    for (int et = 0; et < 4; ++et) {
        float t = ss[et];
        t += __shfl_xor(t, 16); t += __shfl_xor(t, 32);
        ss[et] = t;
    }
    const float m0 = ss[0] / fmaxf((float)(k1[0] - k0[0]), 1.f);
    const float m1 = ss[1] / fmaxf((float)(k1[1] - k0[1]), 1.f);
    const float m2 = ss[2] / fmaxf((float)(k1[2] - k0[2]), 1.f);
    const float m3 = ss[3] / fmaxf((float)(k1[3] - k0[3]), 1.f);
    const float e0 = expf(m0), e1 = expf(m1), e2 = expf(m2), e3 = expf(m3);
    const float wp = 0.6f / (e0 + e1), wn = 0.4f / (e2 + e3);
    const float w0 = e0 * wp, w1 = e1 * wp, w2 = e2 * wn, w3 = e3 * wn;

    float res[8];
    #pragma unroll
    for (int j = 0; j < 8; ++j) {
        float t = w0 * acc[0][j] + w1 * acc[1][j] + w2 * acc[2][j] + w3 * acc[3][j];
        t += __shfl_xor(t, 16); t += __shfl_xor(t, 32);
        res[j] = t;
    }
    if (g == 0) {
        float4 r0 = {res[0], res[1], res[2], res[3]};
        float4 r1 = {res[4], res[5], res[6], res[7]};
        float* o = out + (size_t)d * 256 + 128 + l * 8;
        *(float4*)(o) = r0;
        *(float4*)(o + 4) = r1;
    }
}

// ---------------- oth aggregation (r9-proven, contiguous vulTab) ----------------
__global__ __launch_bounds__(256)
void oth_gather(const int* __restrict__ srcs, const int* __restrict__ offs,
                const unsigned short* __restrict__ vulTab,
                const float* __restrict__ rinHrB,
                const float* __restrict__ rinHtOth,
                float* __restrict__ outO)
{
    const int j = threadIdx.x >> 6;
    const int d = blockIdx.x;
    const int lane = threadIdx.x & 63;
    const int g = lane >> 4, l = lane & 15;

    const float* hrow = outO + ((size_t)j * N_OTH + d) * 256 + l * 8;
    float b0[8];
    {
        float4 t0 = *(const float4*)(hrow);
        float4 t1 = *(const float4*)(hrow + 4);
        b0[0] = t0.x; b0[1] = t0.y; b0[2] = t0.z; b0[3] = t0.w;
        b0[4] = t1.x; b0[5] = t1.y; b0[6] = t1.z; b0[7] = t1.w;
    }
    const float rnb = rinHtOth[j * N_OTH + d];
    const unsigned short* A = vulTab + (size_t)j * NV128;
    const unsigned short* M = vulTab + (size_t)3 * NV128;   // hr_final[0] = We[7] proj
    const float* rA = rinHrB + (size_t)j * N_VUL;

    const int key = VKEYS + j * N_OTH + d;
    const int k0 = offs[key], k1 = offs[key + 1];

    float acc[8];
    #pragma unroll
    for (int jj = 0; jj < 8; ++jj) acc[jj] = 0.f;

    for (int p0 = k0; p0 < k1; p0 += 4) {
        const int p = p0 + g;
        const bool ok = (p < k1);
        const int s = srcs[ok ? p : k0];
        bf16x8 av = *(const bf16x8*)(A + (size_t)s * 128 + l * 8);
        float a[8];
        #pragma unroll
        for (int jj = 0; jj < 8; ++jj) a[jj] = b2f((unsigned short)av[jj]);
        float dp = 0.f;
        #pragma unroll
        for (int jj = 0; jj < 8; ++jj) dp = fmaf(a[jj], b0[jj], dp);
        dp += __shfl_xor(dp, 1); dp += __shfl_xor(dp, 2);
        dp += __shfl_xor(dp, 4); dp += __shfl_xor(dp, 8);
        const float v = ok ? dp * rA[s] * rnb : 0.f;
        if (j == 3) {
            #pragma unroll
            for (int jj = 0; jj < 8; ++jj) acc[jj] = fmaf(v, a[jj], acc[jj]);
        } else {
            bf16x8 mv = *(const bf16x8*)(M + (size_t)s * 128 + l * 8);
            #pragma unroll
            for (int jj = 0; jj < 8; ++jj) acc[jj] = fmaf(v, b2f((unsigned short)mv[jj]), acc[jj]);
        }
    }

    #pragma unroll
    for (int jj = 0; jj < 8; ++jj) {
        float t = acc[jj];
        t += __shfl_xor(t, 16); t += __shfl_xor(t, 32);
        acc[jj] = t;
    }
    if (g == 0) {
        float4 r0 = {acc[0], acc[1], acc[2], acc[3]};
        float4 r1 = {acc[4], acc[5], acc[6], acc[7]};
        float* o = outO + ((size_t)j * N_OTH + d) * 256 + 128 + l * 8;
        *(float4*)(o) = r0;
        *(float4*)(o + 4) = r1;
    }
}

extern "C" void kernel_launch(void* const* d_in, const int* in_sizes, int n_in,
                              void* d_out, int out_size, void* d_ws, size_t ws_size,
                              hipStream_t stream)
{
    // ---- size-based input resolution (proven) ----
    int i_fv = 0, i_fo = 1, i_We = 2, i_Wn = 3, i_bn = 4, i_iA = 5, i_iB = 6;
    {
        int a = -1, b = -1;
        for (int i = 0; i < n_in; ++i) {
            switch (in_sizes[i]) {
                case 25600000: i_fv = i; break;
                case 20480000: i_fo = i; break;
                case   262144: i_We = i; break;
                case   163840: i_Wn = i; break;
                case      640: i_bn = i; break;
                case  3200000: if (a < 0) a = i; else b = i; break;
                default: break;
            }
        }
        if (a >= 0 && b >= 0) { i_iA = a; i_iB = b; }
    }
    const float* feat_vul = (const float*)d_in[i_fv];
    const float* feat_oth = (const float*)d_in[i_fo];
    const float* We = (const float*)d_in[i_We];
    const float* Wn = (const float*)d_in[i_Wn];
    const float* bn = (const float*)d_in[i_bn];
    const int* idxA = (const int*)d_in[i_iA];
    const int* idxB = (const int*)d_in[i_iB];
    float* out = (float*)d_out;

    // ---- workspace carve (~150 MB) ----
    int*      flag    = (int*)d_ws;                       // 4 (zeroed)
    int*      ccnt    = flag + 4;                         // NC (zeroed)
    int*      cbase   = ccnt + NC;                        // NC
    int*      ccur    = cbase + NC;                       // NC
    unsigned* staging = (unsigned*)(ccur + NC);           // TOT_E
    int*      srcs    = (int*)(staging + TOT_E);          // TOT_E
    int*      offs    = srcs + TOT_E;                     // KEYS+1
    float*    rinHtVul = (float*)(offs + KEYS + 1);       // N_VUL
    float*    rinHtOth = rinHtVul + N_VUL;                // 4*N_OTH
    float*    rinHrB   = rinHtOth + (size_t)4 * N_OTH;    // 4*N_VUL
    float*    rinHrS   = rinHrB + (size_t)4 * N_VUL;      // 4*N_OTH
    unsigned short* vulTab = (unsigned short*)(rinHrS + (size_t)4 * N_OTH); // 4*NV128
    unsigned short* othTab = vulTab + 4 * NV128;          // 4*NO128
    unsigned short* Wb     = othTab + 4 * NO128;          // 13*32768

    hipMemsetAsync(d_ws, 0, (4 + (size_t)NC) * sizeof(int), stream);

    probe_idx<<<(E_NUM + 255) / 256, 256, 0, stream>>>(idxA, flag);
    pack_w<<<(13 * 32768 + 255) / 256, 256, 0, stream>>>(We, Wn, Wb);

    const size_t OUT0 = (size_t)N_VUL * 256;

    // projections: vul -> ht(f32)+hrB0..3(bf16); oth i -> ht_i(f32)+hrS_i(bf16)
    proj_mfma<<<(N_VUL + 63) / 64, 256, 0, stream>>>(
        feat_vul, Wb, bn, out, vulTab, 5, N_VUL);
    for (int i = 0; i < 4; ++i)
        proj_mfma<<<(N_OTH + 63) / 64, 256, 0, stream>>>(
            feat_oth + (size_t)i * N_OTH * K_DIM,
            Wb + (size_t)(5 + 2 * i) * 32768,
            bn + (size_t)(i + 1) * D_OUT,
            out + OUT0 + (size_t)i * N_OTH * 256,
            othTab + (size_t)i * NO128, 2, N_OTH);

    // reciprocal norms
    rownorm_f<<<(N_VUL + 3) / 4, 256, 0, stream>>>(out, rinHtVul, N_VUL);
    rownorm_f<<<(4 * N_OTH + 3) / 4, 256, 0, stream>>>(out + OUT0, rinHtOth, 4 * N_OTH);
    rownorm_b<<<(4 * N_VUL + 3) / 4, 256, 0, stream>>>(vulTab, rinHrB, 4 * N_VUL);
    rownorm_b<<<(4 * N_OTH + 3) / 4, 256, 0, stream>>>(othTab, rinHrS, 4 * N_OTH);

    // coarse-bucketed coalesced staging, then per-bucket LDS fine sort -> global CSR
    chist<<<(TOT_E + 16383) / 16384, 256, 0, stream>>>(idxA, idxB, flag, ccnt);
    cscan<<<1, 256, 0, stream>>>(ccnt, cbase, ccur, offs);
    cstage<<<(TOT_E + CHUNK - 1) / CHUNK, 256, 0, stream>>>(idxA, idxB, flag, ccur, staging);
    fine_sort_vul<<<NCV, 256, 0, stream>>>(staging, cbase, ccnt, srcs, offs);
    fine_sort_oth<<<4 * NCO_J, 256, 0, stream>>>(staging, cbase, ccnt, srcs, offs);

    // gathers: vul = r9 structure + first-chunk ILP hoist; oth = r9-proven
    vul_gather<<<N_VUL / 4, 256, 0, stream>>>(srcs, offs, othTab, rinHrS, rinHtVul, out);
    oth_gather<<<N_OTH, 256, 0, stream>>>(srcs, offs, vulTab, rinHrB, rinHtOth, out + OUT0);
}